// Round 18
// baseline (1444.245 us; speedup 1.0000x reference)
//
#include <hip/hip_runtime.h>
#include <math.h>

#define B_    8
#define P_    8192
#define M_    2048
#define NNODE 16384      // B_*M_
#define NCOL  524288     // NNODE*32
#define EPS_  1e-5f

// ---- ws layout (bytes) ----
#define OFF_SX   0ull                        // 65536 f32
#define OFF_KNN  (OFF_SX + 262144ull)        // 524288 i32
#define OFF_FT   (OFF_KNN + 2097152ull)      // 8*8192*64 f32
#define OFF_ST   (OFF_FT + 16777216ull)      // 768 f32 (pad 4096)
#define OFF_AF   (OFF_ST + 4096ull)          // 768 f32 (pad 4096)
#define OFF_W0   (OFF_AF + 4096ull)          // 67*64 f32 = 17152
#define OFF_W1   (OFF_W0 + 17152ull)         // 64*64 f32 = 16384
#define OFF_W2   (OFF_W1 + 16384ull)         // 64*128 f32 = 32768
#define OFF_MULT (OFF_W2 + 32768ull)         // 65536 i32 = 262144
#define OFF_G0   (OFF_MULT + 262144ull)      // 68*68 f32 (pad 18560)
#define OFF_G1   (OFF_G0 + 18560ull)         // 68*68 f32 (pad 18560)
#define OFF_Y1   (OFF_G1 + 18560ull)         // 524288*64 f32 (16B-aligned)
// total ~154 MB

// ---------------- prep ----------------
__global__ __launch_bounds__(256) void k_prep(
    const float* __restrict__ xyz, const float* __restrict__ W0,
    const float* __restrict__ W1, const float* __restrict__ W2,
    float* __restrict__ sx, float* __restrict__ Wt0, float* __restrict__ Wt1,
    float* __restrict__ Wt2, float* __restrict__ stats, float* __restrict__ centers_out,
    int* __restrict__ mult, float* __restrict__ G0, float* __restrict__ G1)
{
  int idx = blockIdx.x*256 + threadIdx.x;
  if (idx < B_*P_) {
    const float* p3 = xyz + (size_t)idx*3;
    float x = p3[0], y = p3[1], z = p3[2];
    sx[idx] = __fadd_rn(__fadd_rn(__fmul_rn(x,x), __fmul_rn(y,y)), __fmul_rn(z,z));
    mult[idx] = 0;
  }
  if (idx < NNODE*3) {
    int m2 = idx/3, comp = idx - m2*3;
    int b = m2 >> 11, m = m2 & 2047;
    int cp = (m * 8191) / 2047;   // exact floor == int32(linspace), verified
    centers_out[idx] = xyz[((size_t)(b*P_ + cp))*3 + comp];
  }
  if (idx < 67*64) { int c = idx >> 6, o = idx & 63;  Wt0[idx] = W0[o*67 + c]; }
  if (idx < 64*64) { int c = idx >> 6, o = idx & 63;  Wt1[idx] = W1[o*64 + c]; }
  if (idx < 64*128){ int c = idx >> 7, o = idx & 127; Wt2[idx] = W2[o*64 + c]; }
  if (idx < 768)   stats[idx] = 0.f;
  if (idx < 4624)  { G0[idx] = 0.f; G1[idx] = 0.f; }
}

// ---------------- feats (b,c,p) -> ft (b,p,c) ----------------
__global__ __launch_bounds__(256) void k_ft(const float* __restrict__ feats, float* __restrict__ ft)
{
  int blk = blockIdx.x;            // 8*128
  int b = blk >> 7; int pt = (blk & 127) * 64;
  __shared__ float tile[64][65];
  const float* fb = feats + (size_t)b*64*P_;
  int tid = threadIdx.x;
  #pragma unroll
  for (int i = 0; i < 16; ++i) {
    int idx = i*256 + tid; int c = idx >> 6, p = idx & 63;
    tile[c][p] = fb[(size_t)c*P_ + pt + p];
  }
  __syncthreads();
  float* fo = ft + ((size_t)b*P_ + pt)*64;
  #pragma unroll
  for (int i = 0; i < 16; ++i) {
    int idx = i*256 + tid; int p = idx >> 6, c = idx & 63;
    fo[(size_t)p*64 + c] = tile[c][p];
  }
}

// ---------------- KNN v3 + fused mult histogram (VERIFIED r17) ----------------
__global__ __launch_bounds__(256) void k_knn(const float* __restrict__ xyz,
                                             const float* __restrict__ sx,
                                             int* __restrict__ knn,
                                             int* __restrict__ mult)
{
  const int tid = threadIdx.x;
  const int lane = tid & 63, w = tid >> 6;
  const int cid = blockIdx.x*4 + w;
  const int b = cid >> 11, m = cid & 2047;
  const int cp = (m * 8191) / 2047;
  const float* xb  = xyz + (size_t)b * P_ * 3;
  const float* sxb = sx + b * P_;
  const float cx = xb[cp*3+0], cy = xb[cp*3+1], cz = xb[cp*3+2];
  const float sc = sxb[cp];
  const unsigned long long EMPTY = ~0ull;

  unsigned long long l0 = EMPTY, l1 = EMPTY, l2 = EMPTY, l3 = EMPTY;

  #pragma unroll 4
  for (int i = 0; i < 128; ++i) {
    int p = i*64 + lane;
    float px = xb[p*3+0], py = xb[p*3+1], pz = xb[p*3+2];
    float dot = fmaf(cz, pz, fmaf(cy, py, __fmul_rn(cx, px)));
    float fk  = __fsub_rn(__fadd_rn(sc, sxb[p]), __fmul_rn(2.0f, dot));
    unsigned ub = __float_as_uint(fk);
    unsigned su = ub ^ (0x80000000u | (unsigned)((int)ub >> 31));  // sortable f32
    unsigned long long k = ((unsigned long long)su << 13) | (unsigned)p;
    unsigned long long m3 = k < l3 ? k : l3;
    bool c2 = m3 < l2;
    unsigned long long n2 = c2 ? m3 : l2, n3 = c2 ? l2 : m3;
    bool c1 = n2 < l1;
    unsigned long long n1 = c1 ? n2 : l1; n2 = c1 ? l1 : n2;
    bool c0 = n1 < l0;
    unsigned long long nl0 = c0 ? n1 : l0; n1 = c0 ? l0 : n1;
    l0 = nl0; l1 = n1; l2 = n2; l3 = n3;
  }

  int* kout = knn + cid*32;
  for (int r = 0; r < 32; ++r) {
    unsigned long long mn = l0;
    #pragma unroll
    for (int off = 1; off < 64; off <<= 1) {
      unsigned long long o = __shfl_xor(mn, off, 64);
      if (o < mn) mn = o;
    }
    if (lane == 0) kout[r] = (int)(mn & 8191u);
    bool mine = ((int)(mn & 63u) == lane);
    if (mine) {
      atomicAdd(&mult[b*P_ + (int)(mn & 8191u)], 1);   // fused histogram
      l0 = l1; l1 = l2; l2 = l3; l3 = EMPTY;
    }
    if (mine && l0 == EMPTY) {
      #pragma unroll 1
      for (int i = 0; i < 128; ++i) {
        int p = i*64 + lane;
        float px = xb[p*3+0], py = xb[p*3+1], pz = xb[p*3+2];
        float dot = fmaf(cz, pz, fmaf(cy, py, __fmul_rn(cx, px)));
        float fk  = __fsub_rn(__fadd_rn(sc, sxb[p]), __fmul_rn(2.0f, dot));
        unsigned ub = __float_as_uint(fk);
        unsigned su = ub ^ (0x80000000u | (unsigned)((int)ub >> 31));
        unsigned long long k = ((unsigned long long)su << 13) | (unsigned)p;
        k = (k > mn) ? k : EMPTY;
        unsigned long long m3 = k < l3 ? k : l3;
        bool c2 = m3 < l2;
        unsigned long long n2 = c2 ? m3 : l2, n3 = c2 ? l2 : m3;
        bool c1 = n2 < l1;
        unsigned long long n1 = c1 ? n2 : l1; n2 = c1 ? l1 : n2;
        bool c0 = n1 < l0;
        unsigned long long nl0 = c0 ? n1 : l0; n1 = c0 ? l0 : n1;
        l0 = nl0; l1 = n1; l2 = n2; l3 = n3;
      }
    }
  }
}

// ---------------- k_gram0: weighted Gram, UPPER TRIANGLE (153 tiles) ----------------
__global__ __launch_bounds__(256) void k_gram0(
    const float* __restrict__ xyz, const float* __restrict__ ft,
    const int* __restrict__ mult, float* __restrict__ G0)
{
  __shared__ float X[64*68];
  __shared__ float ML[64];
  const int tid = threadIdx.x;
  int rem = tid, ta = 0;
  while (ta < 16 && rem >= 17 - ta) { rem -= 17 - ta; ++ta; }
  const int tb = ta + rem;                 // tb >= ta
  const bool act = (tid < 153);
  float acc[16];
  #pragma unroll
  for (int i = 0; i < 16; ++i) acc[i] = 0.f;
  const float4* X4 = (const float4*)X;

  for (int ch = 0; ch < 16; ++ch) {
    int q0 = blockIdx.x*1024 + ch*64;
    __syncthreads();
    {
      int lp = tid >> 2, part = tid & 3;
      int q = q0 + lp; int b = q >> 13, p = q & 8191;
      const float4* fp4 = (const float4*)(ft + ((size_t)(b*P_ + p))*64 + part*16);
      #pragma unroll
      for (int j4 = 0; j4 < 4; ++j4) {
        float4 v = fp4[j4];
        int c = 3 + part*16 + j4*4;
        X[lp*68 + c+0] = v.x; X[lp*68 + c+1] = v.y;
        X[lp*68 + c+2] = v.z; X[lp*68 + c+3] = v.w;
      }
      if (part == 0) {
        const float* xp = xyz + ((size_t)(b*P_ + p))*3;
        X[lp*68 + 0] = xp[0]; X[lp*68 + 1] = xp[1]; X[lp*68 + 2] = xp[2];
      }
      if (part == 1) X[lp*68 + 67] = 1.f;
      if (part == 2) ML[lp] = (float)mult[b*P_ + p];
    }
    __syncthreads();
    if (act) {
      for (int lp = 0; lp < 64; ++lp) {
        float mw = ML[lp];
        float4 xa = X4[lp*17 + ta];
        float4 xb = X4[lp*17 + tb];
        float wa0 = xa.x*mw, wa1 = xa.y*mw, wa2 = xa.z*mw, wa3 = xa.w*mw;
        acc[0]  = fmaf(wa0, xb.x, acc[0]);  acc[1]  = fmaf(wa0, xb.y, acc[1]);
        acc[2]  = fmaf(wa0, xb.z, acc[2]);  acc[3]  = fmaf(wa0, xb.w, acc[3]);
        acc[4]  = fmaf(wa1, xb.x, acc[4]);  acc[5]  = fmaf(wa1, xb.y, acc[5]);
        acc[6]  = fmaf(wa1, xb.z, acc[6]);  acc[7]  = fmaf(wa1, xb.w, acc[7]);
        acc[8]  = fmaf(wa2, xb.x, acc[8]);  acc[9]  = fmaf(wa2, xb.y, acc[9]);
        acc[10] = fmaf(wa2, xb.z, acc[10]); acc[11] = fmaf(wa2, xb.w, acc[11]);
        acc[12] = fmaf(wa3, xb.x, acc[12]); acc[13] = fmaf(wa3, xb.y, acc[13]);
        acc[14] = fmaf(wa3, xb.z, acc[14]); acc[15] = fmaf(wa3, xb.w, acc[15]);
      }
    }
  }
  if (act) {
    #pragma unroll
    for (int i = 0; i < 4; ++i)
      #pragma unroll
      for (int j = 0; j < 4; ++j)
        atomicAdd(&G0[(ta*4+i)*68 + tb*4+j], acc[i*4+j]);
  }
}

// ---------------- k_fin0: stats0 from G0 (symmetric reads, f64) -> aff0 ----------------
__global__ void k_fin0(const float* __restrict__ G, const float* __restrict__ W0,
                       const float* __restrict__ b0, const float* __restrict__ g,
                       const float* __restrict__ be, float* __restrict__ aff)
{
  int o = threadIdx.x;
  if (o < 64) {
    const float* w = W0 + o*67;
    double ws = 0.0;
    for (int c = 0; c < 67; ++c) ws += (double)w[c] * (double)G[c*68 + 67];
    double quad = 0.0;
    for (int c = 0; c < 67; ++c) {
      double row = 0.0;
      for (int d = 0; d < 67; ++d) {
        float gv = (c <= d) ? G[c*68 + d] : G[d*68 + c];
        row += (double)w[d] * (double)gv;
      }
      quad += (double)w[c] * row;
    }
    double N = (double)NCOL, bb = (double)b0[o];
    double sum = ws + N*bb;
    double sq  = quad + 2.0*bb*ws + N*bb*bb;
    double mu = sum/N, var = sq/N - mu*mu;
    float r = 1.0f / sqrtf((float)var + EPS_);
    float s = g[o]*r;
    aff[o] = s;
    aff[128+o] = fmaf(-(float)mu, s, be[o]);
  }
}

// ========== k_g01 (r14-verified): conv0 -> bn0/relu -> conv1, grid-stride 768 ==========
__global__ __launch_bounds__(256) void k_g01(
    const float* __restrict__ xyz, const float* __restrict__ ft,
    const int* __restrict__ knn, const float* __restrict__ Wt0,
    const float* __restrict__ b0, const float* __restrict__ aff0,
    const float* __restrict__ Wt1, const float* __restrict__ b1,
    float* __restrict__ y1, float* __restrict__ stats1)
{
  __shared__ float S[67*66];             // X0T [67][66] then A0T [64][66]
  __shared__ float W0L[67*64];
  __shared__ float W1L[64*64];
  const int tid = threadIdx.x, lane = tid & 63;
  for (int i = tid; i < 67*64; i += 256) W0L[i] = Wt0[i];
  for (int i = tid; i < 64*64; i += 256) W1L[i] = Wt1[i];
  const float4* W0L4 = (const float4*)W0L;
  const float4* W1L4 = (const float4*)W1L;

  const int col0 = 2*(lane & 31);        // 64 cols
  const int og   = tid >> 5;             // 8 out-groups x 8
  const int ob   = og * 8;
  float ts[8], tq[8];
  #pragma unroll
  for (int i = 0; i < 8; ++i) { ts[i] = 0.f; tq[i] = 0.f; }

  for (int t = blockIdx.x; t < 8192; t += 768) {   // 8192 tiles of 64 cols
    int gcol = t*64;
    int b = gcol >> 16;
    __syncthreads();
    {   // stage gather: col = tid&63, q = tid>>6
      int scol = tid & 63, q = tid >> 6;
      int p = knn[gcol + scol];
      if (q == 0) {
        const float* xp = xyz + ((size_t)(b*P_ + p))*3;
        S[0*66 + scol] = xp[0];
        S[1*66 + scol] = xp[1];
        S[2*66 + scol] = xp[2];
      }
      const float4* fp4 = (const float4*)(ft + ((size_t)(b*P_ + p))*64 + q*16);
      #pragma unroll
      for (int j4 = 0; j4 < 4; ++j4) {
        float4 v = fp4[j4];
        int r = 3 + q*16 + j4*4;
        S[(r+0)*66 + scol] = v.x;
        S[(r+1)*66 + scol] = v.y;
        S[(r+2)*66 + scol] = v.z;
        S[(r+3)*66 + scol] = v.w;
      }
    }
    __syncthreads();
    // conv0 GEMM
    float acc0[8], acc1[8];
    #pragma unroll
    for (int i = 0; i < 8; ++i) { acc0[i] = b0[ob+i]; acc1[i] = acc0[i]; }
    for (int c = 0; c < 67; ++c) {
      float2 xp = *(const float2*)(S + c*66 + col0);
      float x0 = xp.x, x1 = xp.y;
      #pragma unroll
      for (int i4 = 0; i4 < 2; ++i4) {
        float4 w = W0L4[c*16 + og*2 + i4];
        acc0[i4*4+0] = fmaf(w.x, x0, acc0[i4*4+0]); acc1[i4*4+0] = fmaf(w.x, x1, acc1[i4*4+0]);
        acc0[i4*4+1] = fmaf(w.y, x0, acc0[i4*4+1]); acc1[i4*4+1] = fmaf(w.y, x1, acc1[i4*4+1]);
        acc0[i4*4+2] = fmaf(w.z, x0, acc0[i4*4+2]); acc1[i4*4+2] = fmaf(w.z, x1, acc1[i4*4+2]);
        acc0[i4*4+3] = fmaf(w.w, x0, acc0[i4*4+3]); acc1[i4*4+3] = fmaf(w.w, x1, acc1[i4*4+3]);
      }
    }
    // bn0 + relu
    #pragma unroll
    for (int i = 0; i < 8; ++i) {
      int o = ob + i;
      acc0[i] = fmaxf(fmaf(acc0[i], aff0[o], aff0[128+o]), 0.f);
      acc1[i] = fmaxf(fmaf(acc1[i], aff0[o], aff0[128+o]), 0.f);
    }
    __syncthreads();                     // all X0T reads done before overwrite
    #pragma unroll
    for (int i = 0; i < 8; ++i)
      *(float2*)(S + (ob+i)*66 + col0) = make_float2(acc0[i], acc1[i]);
    __syncthreads();
    // conv1 GEMM
    float d0[8], d1[8];
    #pragma unroll
    for (int i = 0; i < 8; ++i) { d0[i] = b1[ob+i]; d1[i] = d0[i]; }
    for (int c = 0; c < 64; ++c) {
      float2 xp = *(const float2*)(S + c*66 + col0);
      float x0 = xp.x, x1 = xp.y;
      #pragma unroll
      for (int i4 = 0; i4 < 2; ++i4) {
        float4 w = W1L4[c*16 + og*2 + i4];
        d0[i4*4+0] = fmaf(w.x, x0, d0[i4*4+0]); d1[i4*4+0] = fmaf(w.x, x1, d1[i4*4+0]);
        d0[i4*4+1] = fmaf(w.y, x0, d0[i4*4+1]); d1[i4*4+1] = fmaf(w.y, x1, d1[i4*4+1]);
        d0[i4*4+2] = fmaf(w.z, x0, d0[i4*4+2]); d1[i4*4+2] = fmaf(w.z, x1, d1[i4*4+2]);
        d0[i4*4+3] = fmaf(w.w, x0, d0[i4*4+3]); d1[i4*4+3] = fmaf(w.w, x1, d1[i4*4+3]);
      }
    }
    // store y1 + accumulate stats1
    float* yr0 = y1 + (size_t)(gcol + col0)*64 + ob;
    *(float4*)(yr0)     = make_float4(d0[0], d0[1], d0[2], d0[3]);
    *(float4*)(yr0 + 4) = make_float4(d0[4], d0[5], d0[6], d0[7]);
    float* yr1 = y1 + (size_t)(gcol + col0 + 1)*64 + ob;
    *(float4*)(yr1)     = make_float4(d1[0], d1[1], d1[2], d1[3]);
    *(float4*)(yr1 + 4) = make_float4(d1[4], d1[5], d1[6], d1[7]);
    #pragma unroll
    for (int i = 0; i < 8; ++i) {
      ts[i] += d0[i] + d1[i];
      tq[i] += d0[i]*d0[i] + d1[i]*d1[i];
    }
  }
  #pragma unroll
  for (int i = 0; i < 8; ++i) {
    float s = ts[i], q = tq[i];
    #pragma unroll
    for (int off = 1; off < 32; off <<= 1) {
      s += __shfl_xor(s, off, 64);
      q += __shfl_xor(q, off, 64);
    }
    if ((lane & 31) == 0) { atomicAdd(&stats1[ob+i], s); atomicAdd(&stats1[128+ob+i], q); }
  }
}

// ---------------- BN finalize (layer 1, from direct stats) ----------------
__global__ void k_fin(const float* __restrict__ stats, const float* __restrict__ g,
                      const float* __restrict__ be, float* __restrict__ aff, int C)
{
  int o = threadIdx.x;
  if (o < C) {
    float N = (float)NCOL;
    float mu = stats[o] / N;
    float var = stats[128+o]/N - mu*mu;
    float r = 1.0f / sqrtf(var + EPS_);
    float s = g[o]*r;
    aff[o] = s;
    aff[128+o] = fmaf(-mu, s, be[o]);
  }
}

// ---------------- k_gram1: Gram of a1, UPPER TRIANGLE (153 tiles) ----------------
__global__ __launch_bounds__(256) void k_gram1(
    const float* __restrict__ y1, const float* __restrict__ aff1,
    float* __restrict__ G1)
{
  __shared__ float A[64*68];
  const int tid = threadIdx.x;
  int rem = tid, ta = 0;
  while (ta < 16 && rem >= 17 - ta) { rem -= 17 - ta; ++ta; }
  const int tb = ta + rem;                 // tb >= ta
  const bool act = (tid < 153);
  float acc[16];
  #pragma unroll
  for (int i = 0; i < 16; ++i) acc[i] = 0.f;
  const float4* A4 = (const float4*)A;

  for (int ch = 0; ch < 16; ++ch) {
    int gcol = blockIdx.x*1024 + ch*64;
    __syncthreads();
    {
      int lc = tid >> 2, part = tid & 3;
      const float4* yp = (const float4*)(y1 + (size_t)(gcol + lc)*64 + part*16);
      #pragma unroll
      for (int j4 = 0; j4 < 4; ++j4) {
        float4 v = yp[j4];
        int c = part*16 + j4*4;
        A[lc*68 + c+0] = fmaxf(fmaf(v.x, aff1[c+0], aff1[128+c+0]), 0.f);
        A[lc*68 + c+1] = fmaxf(fmaf(v.y, aff1[c+1], aff1[128+c+1]), 0.f);
        A[lc*68 + c+2] = fmaxf(fmaf(v.z, aff1[c+2], aff1[128+c+2]), 0.f);
        A[lc*68 + c+3] = fmaxf(fmaf(v.w, aff1[c+3], aff1[128+c+3]), 0.f);
      }
      if (part == 1) A[lc*68 + 64] = 1.f;
      if (part == 2) { A[lc*68 + 65] = 0.f; A[lc*68 + 66] = 0.f; A[lc*68 + 67] = 0.f; }
    }
    __syncthreads();
    if (act) {
      for (int lc = 0; lc < 64; ++lc) {
        float4 xa = A4[lc*17 + ta];
        float4 xb = A4[lc*17 + tb];
        acc[0]  = fmaf(xa.x, xb.x, acc[0]);  acc[1]  = fmaf(xa.x, xb.y, acc[1]);
        acc[2]  = fmaf(xa.x, xb.z, acc[2]);  acc[3]  = fmaf(xa.x, xb.w, acc[3]);
        acc[4]  = fmaf(xa.y, xb.x, acc[4]);  acc[5]  = fmaf(xa.y, xb.y, acc[5]);
        acc[6]  = fmaf(xa.y, xb.z, acc[6]);  acc[7]  = fmaf(xa.y, xb.w, acc[7]);
        acc[8]  = fmaf(xa.z, xb.x, acc[8]);  acc[9]  = fmaf(xa.z, xb.y, acc[9]);
        acc[10] = fmaf(xa.z, xb.z, acc[10]); acc[11] = fmaf(xa.z, xb.w, acc[11]);
        acc[12] = fmaf(xa.w, xb.x, acc[12]); acc[13] = fmaf(xa.w, xb.y, acc[13]);
        acc[14] = fmaf(xa.w, xb.z, acc[14]); acc[15] = fmaf(xa.w, xb.w, acc[15]);
      }
    }
  }
  if (act) {
    #pragma unroll
    for (int i = 0; i < 4; ++i)
      #pragma unroll
      for (int j = 0; j < 4; ++j)
        atomicAdd(&G1[(ta*4+i)*68 + tb*4+j], acc[i*4+j]);
  }
}

// ---------------- k_fin2: stats2 from G1 (symmetric reads, f64) -> aff2 ----------------
__global__ void k_fin2(const float* __restrict__ G, const float* __restrict__ W2,
                       const float* __restrict__ b2, const float* __restrict__ g,
                       const float* __restrict__ be, float* __restrict__ aff)
{
  int o = threadIdx.x;
  if (o < 128) {
    const float* w = W2 + o*64;
    double ws = 0.0;
    for (int c = 0; c < 64; ++c) ws += (double)w[c] * (double)G[c*68 + 64];
    double quad = 0.0;
    for (int c = 0; c < 64; ++c) {
      double row = 0.0;
      for (int d = 0; d < 64; ++d) {
        float gv = (c <= d) ? G[c*68 + d] : G[d*68 + c];
        row += (double)w[d] * (double)gv;
      }
      quad += (double)w[c] * row;
    }
    double N = (double)NCOL, bb = (double)b2[o];
    double sum = ws + N*bb;
    double sq  = quad + 2.0*bb*ws + N*bb*bb;
    double mu = sum/N, var = sq/N - mu*mu;
    float r = 1.0f / sqrtf((float)var + EPS_);
    float s = g[o]*r;
    aff[o] = s;
    aff[128+o] = fmaf(-(float)mu, s, be[o]);
  }
}

// ========== shared stage for conv2: bn1(y1) -> XT[64][66] (r10-verified) ==========
__device__ __forceinline__ void stage_bn1(const float* __restrict__ y1,
                                          const float* __restrict__ aff1,
                                          float* __restrict__ XT, int gcol, int tid)
{
  int scol = tid & 63, q = tid >> 6;
  const float4* yp = (const float4*)(y1 + (size_t)(gcol + scol)*64 + q*16);
  #pragma unroll
  for (int j4 = 0; j4 < 4; ++j4) {
    float4 v = yp[j4];
    int c = q*16 + j4*4;
    XT[(c+0)*66 + scol] = fmaxf(fmaf(v.x, aff1[c+0], aff1[128+c+0]), 0.f);
    XT[(c+1)*66 + scol] = fmaxf(fmaf(v.y, aff1[c+1], aff1[128+c+1]), 0.f);
    XT[(c+2)*66 + scol] = fmaxf(fmaf(v.z, aff1[c+2], aff1[128+c+2]), 0.f);
    XT[(c+3)*66 + scol] = fmaxf(fmaf(v.w, aff1[c+3], aff1[128+c+3]), 0.f);
  }
}

// ========== k_g2m (r14-verified): bn1 -> conv2 -> bn2/relu -> max, grid-stride 768 ==========
__global__ __launch_bounds__(256) void k_g2m(
    const float* __restrict__ y1, const float* __restrict__ aff1,
    const float* __restrict__ Wt2, const float* __restrict__ b2,
    const float* __restrict__ aff2, float* __restrict__ out)
{
  __shared__ float XT[64*66];
  __shared__ float W2L[64*128];
  const int tid = threadIdx.x, lane = tid & 63;
  for (int i = tid; i < 64*128; i += 256) W2L[i] = Wt2[i];
  const float4* W2L4 = (const float4*)W2L;

  const int col0 = 2*(lane & 31);
  const int ob   = (tid >> 6)*32 + (lane >> 5)*16;

  for (int t = blockIdx.x; t < 8192; t += 768) {   // 8192 tiles of 64 cols
    int gcol = t*64;
    __syncthreads();
    stage_bn1(y1, aff1, XT, gcol, tid);
    __syncthreads();
    float acc0[16], acc1[16];
    #pragma unroll
    for (int i = 0; i < 16; ++i) { acc0[i] = b2[ob+i]; acc1[i] = acc0[i]; }
    for (int c = 0; c < 64; ++c) {
      float x0 = XT[c*66 + col0];
      float x1 = XT[c*66 + col0 + 1];
      #pragma unroll
      for (int i4 = 0; i4 < 4; ++i4) {
        float4 w = W2L4[c*32 + (ob>>2) + i4];
        acc0[i4*4+0] = fmaf(w.x, x0, acc0[i4*4+0]); acc1[i4*4+0] = fmaf(w.x, x1, acc1[i4*4+0]);
        acc0[i4*4+1] = fmaf(w.y, x0, acc0[i4*4+1]); acc1[i4*4+1] = fmaf(w.y, x1, acc1[i4*4+1]);
        acc0[i4*4+2] = fmaf(w.z, x0, acc0[i4*4+2]); acc1[i4*4+2] = fmaf(w.z, x1, acc1[i4*4+2]);
        acc0[i4*4+3] = fmaf(w.w, x0, acc0[i4*4+3]); acc1[i4*4+3] = fmaf(w.w, x1, acc1[i4*4+3]);
      }
    }
    // bn2 + relu + max over the 2 cols, then over 16-lane groups (one node each)
    float v[16];
    #pragma unroll
    for (int i = 0; i < 16; ++i) {
      int o = ob + i;
      float r0 = fmaxf(fmaf(acc0[i], aff2[o], aff2[128+o]), 0.f);
      float r1 = fmaxf(fmaf(acc1[i], aff2[o], aff2[128+o]), 0.f);
      v[i] = fmaxf(r0, r1);
      #pragma unroll
      for (int off = 1; off < 16; off <<= 1)
        v[i] = fmaxf(v[i], __shfl_xor(v[i], off, 64));
    }
    if ((lane & 15) == 0) {
      int node = (gcol >> 5) + ((lane >> 4) & 1);
      int b = node >> 11, m = node & 2047;
      float* op = out + ((size_t)b*128)*2048 + m;
      #pragma unroll
      for (int i = 0; i < 16; ++i)
        op[(size_t)(ob+i)*2048] = v[i];
    }
  }
}

extern "C" void kernel_launch(void* const* d_in, const int* in_sizes, int n_in,
                              void* d_out, int out_size, void* d_ws, size_t ws_size,
                              hipStream_t stream)
{
  const float* xyz   = (const float*)d_in[0];
  const float* feats = (const float*)d_in[1];
  const float* W0 = (const float*)d_in[2];
  const float* b0 = (const float*)d_in[3];
  const float* g0 = (const float*)d_in[4];
  const float* be0= (const float*)d_in[5];
  const float* W1 = (const float*)d_in[6];
  const float* b1 = (const float*)d_in[7];
  const float* g1 = (const float*)d_in[8];
  const float* be1= (const float*)d_in[9];
  const float* W2 = (const float*)d_in[10];
  const float* b2 = (const float*)d_in[11];
  const float* g2 = (const float*)d_in[12];
  const float* be2= (const float*)d_in[13];

  char* ws = (char*)d_ws;
  float* sx    = (float*)(ws + OFF_SX);
  int*   knn   = (int*  )(ws + OFF_KNN);
  float* ft    = (float*)(ws + OFF_FT);
  float* stats = (float*)(ws + OFF_ST);
  float* aff   = (float*)(ws + OFF_AF);
  float* Wt0   = (float*)(ws + OFF_W0);
  float* Wt1   = (float*)(ws + OFF_W1);
  float* Wt2   = (float*)(ws + OFF_W2);
  int*   mult  = (int*  )(ws + OFF_MULT);
  float* G0    = (float*)(ws + OFF_G0);
  float* G1    = (float*)(ws + OFF_G1);
  float* y1    = (float*)(ws + OFF_Y1);

  float* centers_out = (float*)d_out;              // 8*2048*3
  float* feat_out    = (float*)d_out + NNODE*3;    // 8*128*2048

  k_prep <<<256, 256, 0, stream>>>(xyz, W0, W1, W2, sx, Wt0, Wt1, Wt2, stats,
                                   centers_out, mult, G0, G1);
  k_ft   <<<1024, 256, 0, stream>>>(feats, ft);
  k_knn  <<<NNODE/4, 256, 0, stream>>>(xyz, sx, knn, mult);
  k_gram0<<<64, 256, 0, stream>>>(xyz, ft, mult, G0);
  k_fin0 <<<1, 64, 0, stream>>>(G0, W0, b0, g0, be0, aff + 0);
  k_g01  <<<768, 256, 0, stream>>>(xyz, ft, knn, Wt0, b0, aff + 0, Wt1, b1, y1, stats + 256);
  k_fin  <<<1, 128, 0, stream>>>(stats + 256, g1, be1, aff + 256, 64);
  k_gram1<<<512, 256, 0, stream>>>(y1, aff + 256, G1);
  k_fin2 <<<1, 128, 0, stream>>>(G1, W2, b2, g2, be2, aff + 512);
  k_g2m  <<<768, 256, 0, stream>>>(y1, aff + 256, Wt2, b2, aff + 512, feat_out);
}

// Round 19
// 987.833 us; speedup vs baseline: 1.4620x; 1.4620x over previous
//
#include <hip/hip_runtime.h>
#include <math.h>

#define B_    8
#define P_    8192
#define M_    2048
#define NNODE 16384      // B_*M_
#define NCOL  524288     // NNODE*32
#define EPS_  1e-5f

// ---- ws layout (bytes) ----
#define OFF_SX   0ull                        // 65536 f32
#define OFF_KNN  (OFF_SX + 262144ull)        // 524288 i32
#define OFF_FT   (OFF_KNN + 2097152ull)      // 8*8192*64 f32
#define OFF_ST   (OFF_FT + 16777216ull)      // 768 f32 (pad 4096)
#define OFF_AF   (OFF_ST + 4096ull)          // 768 f32 (pad 4096)
#define OFF_W0   (OFF_AF + 4096ull)          // 67*64 f32 = 17152
#define OFF_W1   (OFF_W0 + 17152ull)         // 64*64 f32 = 16384
#define OFF_W2   (OFF_W1 + 16384ull)         // 64*128 f32 = 32768
#define OFF_MULT (OFF_W2 + 32768ull)         // 65536 i32 = 262144
#define OFF_G0   (OFF_MULT + 262144ull)      // 68*68 f32 (pad 18560)
#define OFF_G1   (OFF_G0 + 18560ull)         // 68*68 f32 (pad 18560)
#define OFF_Y1   (OFF_G1 + 18560ull)         // 524288*64 f32 (16B-aligned)
// total ~154 MB

// ---------------- prep ----------------
__global__ __launch_bounds__(256) void k_prep(
    const float* __restrict__ xyz, const float* __restrict__ W0,
    const float* __restrict__ W1, const float* __restrict__ W2,
    float* __restrict__ sx, float* __restrict__ Wt0, float* __restrict__ Wt1,
    float* __restrict__ Wt2, float* __restrict__ stats, float* __restrict__ centers_out,
    int* __restrict__ mult, float* __restrict__ G0, float* __restrict__ G1)
{
  int idx = blockIdx.x*256 + threadIdx.x;
  if (idx < B_*P_) {
    const float* p3 = xyz + (size_t)idx*3;
    float x = p3[0], y = p3[1], z = p3[2];
    sx[idx] = __fadd_rn(__fadd_rn(__fmul_rn(x,x), __fmul_rn(y,y)), __fmul_rn(z,z));
    mult[idx] = 0;
  }
  if (idx < NNODE*3) {
    int m2 = idx/3, comp = idx - m2*3;
    int b = m2 >> 11, m = m2 & 2047;
    int cp = (m * 8191) / 2047;   // exact floor == int32(linspace), verified
    centers_out[idx] = xyz[((size_t)(b*P_ + cp))*3 + comp];
  }
  if (idx < 67*64) { int c = idx >> 6, o = idx & 63;  Wt0[idx] = W0[o*67 + c]; }
  if (idx < 64*64) { int c = idx >> 6, o = idx & 63;  Wt1[idx] = W1[o*64 + c]; }
  if (idx < 64*128){ int c = idx >> 7, o = idx & 127; Wt2[idx] = W2[o*64 + c]; }
  if (idx < 768)   stats[idx] = 0.f;
  if (idx < 4624)  { G0[idx] = 0.f; G1[idx] = 0.f; }
}

// ---------------- feats (b,c,p) -> ft (b,p,c) ----------------
__global__ __launch_bounds__(256) void k_ft(const float* __restrict__ feats, float* __restrict__ ft)
{
  int blk = blockIdx.x;            // 8*128
  int b = blk >> 7; int pt = (blk & 127) * 64;
  __shared__ float tile[64][65];
  const float* fb = feats + (size_t)b*64*P_;
  int tid = threadIdx.x;
  #pragma unroll
  for (int i = 0; i < 16; ++i) {
    int idx = i*256 + tid; int c = idx >> 6, p = idx & 63;
    tile[c][p] = fb[(size_t)c*P_ + pt + p];
  }
  __syncthreads();
  float* fo = ft + ((size_t)b*P_ + pt)*64;
  #pragma unroll
  for (int i = 0; i < 16; ++i) {
    int idx = i*256 + tid; int p = idx >> 6, c = idx & 63;
    fo[(size_t)p*64 + c] = tile[c][p];
  }
}

// ---------------- KNN v3 + fused mult histogram (VERIFIED r17) ----------------
__global__ __launch_bounds__(256) void k_knn(const float* __restrict__ xyz,
                                             const float* __restrict__ sx,
                                             int* __restrict__ knn,
                                             int* __restrict__ mult)
{
  const int tid = threadIdx.x;
  const int lane = tid & 63, w = tid >> 6;
  const int cid = blockIdx.x*4 + w;
  const int b = cid >> 11, m = cid & 2047;
  const int cp = (m * 8191) / 2047;
  const float* xb  = xyz + (size_t)b * P_ * 3;
  const float* sxb = sx + b * P_;
  const float cx = xb[cp*3+0], cy = xb[cp*3+1], cz = xb[cp*3+2];
  const float sc = sxb[cp];
  const unsigned long long EMPTY = ~0ull;

  unsigned long long l0 = EMPTY, l1 = EMPTY, l2 = EMPTY, l3 = EMPTY;

  #pragma unroll 4
  for (int i = 0; i < 128; ++i) {
    int p = i*64 + lane;
    float px = xb[p*3+0], py = xb[p*3+1], pz = xb[p*3+2];
    float dot = fmaf(cz, pz, fmaf(cy, py, __fmul_rn(cx, px)));
    float fk  = __fsub_rn(__fadd_rn(sc, sxb[p]), __fmul_rn(2.0f, dot));
    unsigned ub = __float_as_uint(fk);
    unsigned su = ub ^ (0x80000000u | (unsigned)((int)ub >> 31));  // sortable f32
    unsigned long long k = ((unsigned long long)su << 13) | (unsigned)p;
    unsigned long long m3 = k < l3 ? k : l3;
    bool c2 = m3 < l2;
    unsigned long long n2 = c2 ? m3 : l2, n3 = c2 ? l2 : m3;
    bool c1 = n2 < l1;
    unsigned long long n1 = c1 ? n2 : l1; n2 = c1 ? l1 : n2;
    bool c0 = n1 < l0;
    unsigned long long nl0 = c0 ? n1 : l0; n1 = c0 ? l0 : n1;
    l0 = nl0; l1 = n1; l2 = n2; l3 = n3;
  }

  int* kout = knn + cid*32;
  for (int r = 0; r < 32; ++r) {
    unsigned long long mn = l0;
    #pragma unroll
    for (int off = 1; off < 64; off <<= 1) {
      unsigned long long o = __shfl_xor(mn, off, 64);
      if (o < mn) mn = o;
    }
    if (lane == 0) kout[r] = (int)(mn & 8191u);
    bool mine = ((int)(mn & 63u) == lane);
    if (mine) {
      atomicAdd(&mult[b*P_ + (int)(mn & 8191u)], 1);   // fused histogram
      l0 = l1; l1 = l2; l2 = l3; l3 = EMPTY;
    }
    if (mine && l0 == EMPTY) {
      #pragma unroll 1
      for (int i = 0; i < 128; ++i) {
        int p = i*64 + lane;
        float px = xb[p*3+0], py = xb[p*3+1], pz = xb[p*3+2];
        float dot = fmaf(cz, pz, fmaf(cy, py, __fmul_rn(cx, px)));
        float fk  = __fsub_rn(__fadd_rn(sc, sxb[p]), __fmul_rn(2.0f, dot));
        unsigned ub = __float_as_uint(fk);
        unsigned su = ub ^ (0x80000000u | (unsigned)((int)ub >> 31));
        unsigned long long k = ((unsigned long long)su << 13) | (unsigned)p;
        k = (k > mn) ? k : EMPTY;
        unsigned long long m3 = k < l3 ? k : l3;
        bool c2 = m3 < l2;
        unsigned long long n2 = c2 ? m3 : l2, n3 = c2 ? l2 : m3;
        bool c1 = n2 < l1;
        unsigned long long n1 = c1 ? n2 : l1; n2 = c1 ? l1 : n2;
        bool c0 = n1 < l0;
        unsigned long long nl0 = c0 ? n1 : l0; n1 = c0 ? l0 : n1;
        l0 = nl0; l1 = n1; l2 = n2; l3 = n3;
      }
    }
  }
}

// ---------------- k_gram0: weighted Gram of X0 (r17-verified full tiles) ----------------
__global__ __launch_bounds__(256) void k_gram0(
    const float* __restrict__ xyz, const float* __restrict__ ft,
    const int* __restrict__ mult, float* __restrict__ G0)
{
  __shared__ float X[64*68];
  __shared__ float ML[64];
  const int tid = threadIdx.x;
  const int t0 = tid;                 // tile ids in [0,289): 17x17 of 4x4
  const int t1 = 256 + tid;           // valid for tid < 33
  const int ta0 = t0/17, tb0 = t0%17;
  const int ta1 = t1/17, tb1 = t1%17;
  float acc0[16], acc1[16];
  #pragma unroll
  for (int i = 0; i < 16; ++i) { acc0[i] = 0.f; acc1[i] = 0.f; }
  const float4* X4 = (const float4*)X;

  for (int ch = 0; ch < 16; ++ch) {
    int q0 = blockIdx.x*1024 + ch*64;
    __syncthreads();
    {
      int lp = tid >> 2, part = tid & 3;
      int q = q0 + lp; int b = q >> 13, p = q & 8191;
      const float4* fp4 = (const float4*)(ft + ((size_t)(b*P_ + p))*64 + part*16);
      #pragma unroll
      for (int j4 = 0; j4 < 4; ++j4) {
        float4 v = fp4[j4];
        int c = 3 + part*16 + j4*4;
        X[lp*68 + c+0] = v.x; X[lp*68 + c+1] = v.y;
        X[lp*68 + c+2] = v.z; X[lp*68 + c+3] = v.w;
      }
      if (part == 0) {
        const float* xp = xyz + ((size_t)(b*P_ + p))*3;
        X[lp*68 + 0] = xp[0]; X[lp*68 + 1] = xp[1]; X[lp*68 + 2] = xp[2];
      }
      if (part == 1) X[lp*68 + 67] = 1.f;
      if (part == 2) ML[lp] = (float)mult[b*P_ + p];
    }
    __syncthreads();
    for (int lp = 0; lp < 64; ++lp) {
      float mw = ML[lp];
      {
        float4 xa = X4[lp*17 + ta0];
        float4 xb = X4[lp*17 + tb0];
        float wa0 = xa.x*mw, wa1 = xa.y*mw, wa2 = xa.z*mw, wa3 = xa.w*mw;
        acc0[0]  = fmaf(wa0, xb.x, acc0[0]);  acc0[1]  = fmaf(wa0, xb.y, acc0[1]);
        acc0[2]  = fmaf(wa0, xb.z, acc0[2]);  acc0[3]  = fmaf(wa0, xb.w, acc0[3]);
        acc0[4]  = fmaf(wa1, xb.x, acc0[4]);  acc0[5]  = fmaf(wa1, xb.y, acc0[5]);
        acc0[6]  = fmaf(wa1, xb.z, acc0[6]);  acc0[7]  = fmaf(wa1, xb.w, acc0[7]);
        acc0[8]  = fmaf(wa2, xb.x, acc0[8]);  acc0[9]  = fmaf(wa2, xb.y, acc0[9]);
        acc0[10] = fmaf(wa2, xb.z, acc0[10]); acc0[11] = fmaf(wa2, xb.w, acc0[11]);
        acc0[12] = fmaf(wa3, xb.x, acc0[12]); acc0[13] = fmaf(wa3, xb.y, acc0[13]);
        acc0[14] = fmaf(wa3, xb.z, acc0[14]); acc0[15] = fmaf(wa3, xb.w, acc0[15]);
      }
      if (tid < 33) {
        float4 xa = X4[lp*17 + ta1];
        float4 xb = X4[lp*17 + tb1];
        float wa0 = xa.x*mw, wa1 = xa.y*mw, wa2 = xa.z*mw, wa3 = xa.w*mw;
        acc1[0]  = fmaf(wa0, xb.x, acc1[0]);  acc1[1]  = fmaf(wa0, xb.y, acc1[1]);
        acc1[2]  = fmaf(wa0, xb.z, acc1[2]);  acc1[3]  = fmaf(wa0, xb.w, acc1[3]);
        acc1[4]  = fmaf(wa1, xb.x, acc1[4]);  acc1[5]  = fmaf(wa1, xb.y, acc1[5]);
        acc1[6]  = fmaf(wa1, xb.z, acc1[6]);  acc1[7]  = fmaf(wa1, xb.w, acc1[7]);
        acc1[8]  = fmaf(wa2, xb.x, acc1[8]);  acc1[9]  = fmaf(wa2, xb.y, acc1[9]);
        acc1[10] = fmaf(wa2, xb.z, acc1[10]); acc1[11] = fmaf(wa2, xb.w, acc1[11]);
        acc1[12] = fmaf(wa3, xb.x, acc1[12]); acc1[13] = fmaf(wa3, xb.y, acc1[13]);
        acc1[14] = fmaf(wa3, xb.z, acc1[14]); acc1[15] = fmaf(wa3, xb.w, acc1[15]);
      }
    }
  }
  #pragma unroll
  for (int i = 0; i < 4; ++i)
    #pragma unroll
    for (int j = 0; j < 4; ++j)
      atomicAdd(&G0[(ta0*4+i)*68 + tb0*4+j], acc0[i*4+j]);
  if (tid < 33) {
    #pragma unroll
    for (int i = 0; i < 4; ++i)
      #pragma unroll
      for (int j = 0; j < 4; ++j)
        atomicAdd(&G0[(ta1*4+i)*68 + tb1*4+j], acc1[i*4+j]);
  }
}

// ---------------- k_fin0 v2: PARALLEL quadform (64 blocks x 64 thr) ----------------
__global__ void k_fin0(const float* __restrict__ G, const float* __restrict__ W0,
                       const float* __restrict__ b0, const float* __restrict__ g,
                       const float* __restrict__ be, float* __restrict__ aff)
{
  const int o = blockIdx.x;          // 64 outputs
  const int c = threadIdx.x;         // 64 threads
  const float* w = W0 + o*67;
  double part = 0.0, wsp = 0.0;
  for (int cc = c; cc < 67; cc += 64) {
    double row = 0.0;
    for (int d = 0; d < 67; ++d) row += (double)w[d] * (double)G[cc*68 + d];
    part += (double)w[cc] * row;
    wsp  += (double)w[cc] * (double)G[cc*68 + 67];
  }
  #pragma unroll
  for (int off = 1; off < 64; off <<= 1) {
    part += __shfl_xor(part, off, 64);
    wsp  += __shfl_xor(wsp,  off, 64);
  }
  if (c == 0) {
    double N = (double)NCOL, bb = (double)b0[o];
    double sum = wsp + N*bb;
    double sq  = part + 2.0*bb*wsp + N*bb*bb;
    double mu = sum/N, var = sq/N - mu*mu;
    float r = 1.0f / sqrtf((float)var + EPS_);
    float s = g[o]*r;
    aff[o] = s;
    aff[128+o] = fmaf(-(float)mu, s, be[o]);
  }
}

// ========== k_g01 (r14-verified): conv0 -> bn0/relu -> conv1, grid-stride 768 ==========
__global__ __launch_bounds__(256) void k_g01(
    const float* __restrict__ xyz, const float* __restrict__ ft,
    const int* __restrict__ knn, const float* __restrict__ Wt0,
    const float* __restrict__ b0, const float* __restrict__ aff0,
    const float* __restrict__ Wt1, const float* __restrict__ b1,
    float* __restrict__ y1, float* __restrict__ stats1)
{
  __shared__ float S[67*66];             // X0T [67][66] then A0T [64][66]
  __shared__ float W0L[67*64];
  __shared__ float W1L[64*64];
  const int tid = threadIdx.x, lane = tid & 63;
  for (int i = tid; i < 67*64; i += 256) W0L[i] = Wt0[i];
  for (int i = tid; i < 64*64; i += 256) W1L[i] = Wt1[i];
  const float4* W0L4 = (const float4*)W0L;
  const float4* W1L4 = (const float4*)W1L;

  const int col0 = 2*(lane & 31);        // 64 cols
  const int og   = tid >> 5;             // 8 out-groups x 8
  const int ob   = og * 8;
  float ts[8], tq[8];
  #pragma unroll
  for (int i = 0; i < 8; ++i) { ts[i] = 0.f; tq[i] = 0.f; }

  for (int t = blockIdx.x; t < 8192; t += 768) {   // 8192 tiles of 64 cols
    int gcol = t*64;
    int b = gcol >> 16;
    __syncthreads();
    {   // stage gather: col = tid&63, q = tid>>6
      int scol = tid & 63, q = tid >> 6;
      int p = knn[gcol + scol];
      if (q == 0) {
        const float* xp = xyz + ((size_t)(b*P_ + p))*3;
        S[0*66 + scol] = xp[0];
        S[1*66 + scol] = xp[1];
        S[2*66 + scol] = xp[2];
      }
      const float4* fp4 = (const float4*)(ft + ((size_t)(b*P_ + p))*64 + q*16);
      #pragma unroll
      for (int j4 = 0; j4 < 4; ++j4) {
        float4 v = fp4[j4];
        int r = 3 + q*16 + j4*4;
        S[(r+0)*66 + scol] = v.x;
        S[(r+1)*66 + scol] = v.y;
        S[(r+2)*66 + scol] = v.z;
        S[(r+3)*66 + scol] = v.w;
      }
    }
    __syncthreads();
    // conv0 GEMM
    float acc0[8], acc1[8];
    #pragma unroll
    for (int i = 0; i < 8; ++i) { acc0[i] = b0[ob+i]; acc1[i] = acc0[i]; }
    for (int c = 0; c < 67; ++c) {
      float2 xp = *(const float2*)(S + c*66 + col0);
      float x0 = xp.x, x1 = xp.y;
      #pragma unroll
      for (int i4 = 0; i4 < 2; ++i4) {
        float4 w = W0L4[c*16 + og*2 + i4];
        acc0[i4*4+0] = fmaf(w.x, x0, acc0[i4*4+0]); acc1[i4*4+0] = fmaf(w.x, x1, acc1[i4*4+0]);
        acc0[i4*4+1] = fmaf(w.y, x0, acc0[i4*4+1]); acc1[i4*4+1] = fmaf(w.y, x1, acc1[i4*4+1]);
        acc0[i4*4+2] = fmaf(w.z, x0, acc0[i4*4+2]); acc1[i4*4+2] = fmaf(w.z, x1, acc1[i4*4+2]);
        acc0[i4*4+3] = fmaf(w.w, x0, acc0[i4*4+3]); acc1[i4*4+3] = fmaf(w.w, x1, acc1[i4*4+3]);
      }
    }
    // bn0 + relu
    #pragma unroll
    for (int i = 0; i < 8; ++i) {
      int o = ob + i;
      acc0[i] = fmaxf(fmaf(acc0[i], aff0[o], aff0[128+o]), 0.f);
      acc1[i] = fmaxf(fmaf(acc1[i], aff0[o], aff0[128+o]), 0.f);
    }
    __syncthreads();                     // all X0T reads done before overwrite
    #pragma unroll
    for (int i = 0; i < 8; ++i)
      *(float2*)(S + (ob+i)*66 + col0) = make_float2(acc0[i], acc1[i]);
    __syncthreads();
    // conv1 GEMM
    float d0[8], d1[8];
    #pragma unroll
    for (int i = 0; i < 8; ++i) { d0[i] = b1[ob+i]; d1[i] = d0[i]; }
    for (int c = 0; c < 64; ++c) {
      float2 xp = *(const float2*)(S + c*66 + col0);
      float x0 = xp.x, x1 = xp.y;
      #pragma unroll
      for (int i4 = 0; i4 < 2; ++i4) {
        float4 w = W1L4[c*16 + og*2 + i4];
        d0[i4*4+0] = fmaf(w.x, x0, d0[i4*4+0]); d1[i4*4+0] = fmaf(w.x, x1, d1[i4*4+0]);
        d0[i4*4+1] = fmaf(w.y, x0, d0[i4*4+1]); d1[i4*4+1] = fmaf(w.y, x1, d1[i4*4+1]);
        d0[i4*4+2] = fmaf(w.z, x0, d0[i4*4+2]); d1[i4*4+2] = fmaf(w.z, x1, d1[i4*4+2]);
        d0[i4*4+3] = fmaf(w.w, x0, d0[i4*4+3]); d1[i4*4+3] = fmaf(w.w, x1, d1[i4*4+3]);
      }
    }
    // store y1 + accumulate stats1
    float* yr0 = y1 + (size_t)(gcol + col0)*64 + ob;
    *(float4*)(yr0)     = make_float4(d0[0], d0[1], d0[2], d0[3]);
    *(float4*)(yr0 + 4) = make_float4(d0[4], d0[5], d0[6], d0[7]);
    float* yr1 = y1 + (size_t)(gcol + col0 + 1)*64 + ob;
    *(float4*)(yr1)     = make_float4(d1[0], d1[1], d1[2], d1[3]);
    *(float4*)(yr1 + 4) = make_float4(d1[4], d1[5], d1[6], d1[7]);
    #pragma unroll
    for (int i = 0; i < 8; ++i) {
      ts[i] += d0[i] + d1[i];
      tq[i] += d0[i]*d0[i] + d1[i]*d1[i];
    }
  }
  #pragma unroll
  for (int i = 0; i < 8; ++i) {
    float s = ts[i], q = tq[i];
    #pragma unroll
    for (int off = 1; off < 32; off <<= 1) {
      s += __shfl_xor(s, off, 64);
      q += __shfl_xor(q, off, 64);
    }
    if ((lane & 31) == 0) { atomicAdd(&stats1[ob+i], s); atomicAdd(&stats1[128+ob+i], q); }
  }
}

// ---------------- BN finalize (layer 1, from direct stats) ----------------
__global__ void k_fin(const float* __restrict__ stats, const float* __restrict__ g,
                      const float* __restrict__ be, float* __restrict__ aff, int C)
{
  int o = threadIdx.x;
  if (o < C) {
    float N = (float)NCOL;
    float mu = stats[o] / N;
    float var = stats[128+o]/N - mu*mu;
    float r = 1.0f / sqrtf(var + EPS_);
    float s = g[o]*r;
    aff[o] = s;
    aff[128+o] = fmaf(-mu, s, be[o]);
  }
}

// ---------------- k_gram1: Gram of a1 (r17-verified full tiles) ----------------
__global__ __launch_bounds__(256) void k_gram1(
    const float* __restrict__ y1, const float* __restrict__ aff1,
    float* __restrict__ G1)
{
  __shared__ float A[64*68];
  const int tid = threadIdx.x;
  const int t0 = tid, t1 = 256 + tid;
  const int ta0 = t0/17, tb0 = t0%17;
  const int ta1 = t1/17, tb1 = t1%17;
  float acc0[16], acc1[16];
  #pragma unroll
  for (int i = 0; i < 16; ++i) { acc0[i] = 0.f; acc1[i] = 0.f; }
  const float4* A4 = (const float4*)A;

  for (int ch = 0; ch < 16; ++ch) {
    int gcol = blockIdx.x*1024 + ch*64;
    __syncthreads();
    {
      int lc = tid >> 2, part = tid & 3;
      const float4* yp = (const float4*)(y1 + (size_t)(gcol + lc)*64 + part*16);
      #pragma unroll
      for (int j4 = 0; j4 < 4; ++j4) {
        float4 v = yp[j4];
        int c = part*16 + j4*4;
        A[lc*68 + c+0] = fmaxf(fmaf(v.x, aff1[c+0], aff1[128+c+0]), 0.f);
        A[lc*68 + c+1] = fmaxf(fmaf(v.y, aff1[c+1], aff1[128+c+1]), 0.f);
        A[lc*68 + c+2] = fmaxf(fmaf(v.z, aff1[c+2], aff1[128+c+2]), 0.f);
        A[lc*68 + c+3] = fmaxf(fmaf(v.w, aff1[c+3], aff1[128+c+3]), 0.f);
      }
      if (part == 1) A[lc*68 + 64] = 1.f;
      if (part == 2) { A[lc*68 + 65] = 0.f; A[lc*68 + 66] = 0.f; A[lc*68 + 67] = 0.f; }
    }
    __syncthreads();
    for (int lc = 0; lc < 64; ++lc) {
      {
        float4 xa = A4[lc*17 + ta0];
        float4 xb = A4[lc*17 + tb0];
        acc0[0]  = fmaf(xa.x, xb.x, acc0[0]);  acc0[1]  = fmaf(xa.x, xb.y, acc0[1]);
        acc0[2]  = fmaf(xa.x, xb.z, acc0[2]);  acc0[3]  = fmaf(xa.x, xb.w, acc0[3]);
        acc0[4]  = fmaf(xa.y, xb.x, acc0[4]);  acc0[5]  = fmaf(xa.y, xb.y, acc0[5]);
        acc0[6]  = fmaf(xa.y, xb.z, acc0[6]);  acc0[7]  = fmaf(xa.y, xb.w, acc0[7]);
        acc0[8]  = fmaf(xa.z, xb.x, acc0[8]);  acc0[9]  = fmaf(xa.z, xb.y, acc0[9]);
        acc0[10] = fmaf(xa.z, xb.z, acc0[10]); acc0[11] = fmaf(xa.z, xb.w, acc0[11]);
        acc0[12] = fmaf(xa.w, xb.x, acc0[12]); acc0[13] = fmaf(xa.w, xb.y, acc0[13]);
        acc0[14] = fmaf(xa.w, xb.z, acc0[14]); acc0[15] = fmaf(xa.w, xb.w, acc0[15]);
      }
      if (tid < 33) {
        float4 xa = A4[lc*17 + ta1];
        float4 xb = A4[lc*17 + tb1];
        acc1[0]  = fmaf(xa.x, xb.x, acc1[0]);  acc1[1]  = fmaf(xa.x, xb.y, acc1[1]);
        acc1[2]  = fmaf(xa.x, xb.z, acc1[2]);  acc1[3]  = fmaf(xa.x, xb.w, acc1[3]);
        acc1[4]  = fmaf(xa.y, xb.x, acc1[4]);  acc1[5]  = fmaf(xa.y, xb.y, acc1[5]);
        acc1[6]  = fmaf(xa.y, xb.z, acc1[6]);  acc1[7]  = fmaf(xa.y, xb.w, acc1[7]);
        acc1[8]  = fmaf(xa.z, xb.x, acc1[8]);  acc1[9]  = fmaf(xa.z, xb.y, acc1[9]);
        acc1[10] = fmaf(xa.z, xb.z, acc1[10]); acc1[11] = fmaf(xa.z, xb.w, acc1[11]);
        acc1[12] = fmaf(xa.w, xb.x, acc1[12]); acc1[13] = fmaf(xa.w, xb.y, acc1[13]);
        acc1[14] = fmaf(xa.w, xb.z, acc1[14]); acc1[15] = fmaf(xa.w, xb.w, acc1[15]);
      }
    }
  }
  #pragma unroll
  for (int i = 0; i < 4; ++i)
    #pragma unroll
    for (int j = 0; j < 4; ++j)
      atomicAdd(&G1[(ta0*4+i)*68 + tb0*4+j], acc0[i*4+j]);
  if (tid < 33) {
    #pragma unroll
    for (int i = 0; i < 4; ++i)
      #pragma unroll
      for (int j = 0; j < 4; ++j)
        atomicAdd(&G1[(ta1*4+i)*68 + tb1*4+j], acc1[i*4+j]);
  }
}

// ---------------- k_fin2 v2: PARALLEL quadform (128 blocks x 64 thr) ----------------
__global__ void k_fin2(const float* __restrict__ G, const float* __restrict__ W2,
                       const float* __restrict__ b2, const float* __restrict__ g,
                       const float* __restrict__ be, float* __restrict__ aff)
{
  const int o = blockIdx.x;          // 128 outputs
  const int c = threadIdx.x;         // 64 threads
  const float* w = W2 + o*64;
  double row = 0.0;
  for (int d = 0; d < 64; ++d) row += (double)w[d] * (double)G[c*68 + d];
  double part = (double)w[c] * row;
  double wsp  = (double)w[c] * (double)G[c*68 + 64];
  #pragma unroll
  for (int off = 1; off < 64; off <<= 1) {
    part += __shfl_xor(part, off, 64);
    wsp  += __shfl_xor(wsp,  off, 64);
  }
  if (c == 0) {
    double N = (double)NCOL, bb = (double)b2[o];
    double sum = wsp + N*bb;
    double sq  = part + 2.0*bb*wsp + N*bb*bb;
    double mu = sum/N, var = sq/N - mu*mu;
    float r = 1.0f / sqrtf((float)var + EPS_);
    float s = g[o]*r;
    aff[o] = s;
    aff[128+o] = fmaf(-(float)mu, s, be[o]);
  }
}

// ========== shared stage for conv2: bn1(y1) -> XT[64][66] (r10-verified) ==========
__device__ __forceinline__ void stage_bn1(const float* __restrict__ y1,
                                          const float* __restrict__ aff1,
                                          float* __restrict__ XT, int gcol, int tid)
{
  int scol = tid & 63, q = tid >> 6;
  const float4* yp = (const float4*)(y1 + (size_t)(gcol + scol)*64 + q*16);
  #pragma unroll
  for (int j4 = 0; j4 < 4; ++j4) {
    float4 v = yp[j4];
    int c = q*16 + j4*4;
    XT[(c+0)*66 + scol] = fmaxf(fmaf(v.x, aff1[c+0], aff1[128+c+0]), 0.f);
    XT[(c+1)*66 + scol] = fmaxf(fmaf(v.y, aff1[c+1], aff1[128+c+1]), 0.f);
    XT[(c+2)*66 + scol] = fmaxf(fmaf(v.z, aff1[c+2], aff1[128+c+2]), 0.f);
    XT[(c+3)*66 + scol] = fmaxf(fmaf(v.w, aff1[c+3], aff1[128+c+3]), 0.f);
  }
}

// ========== k_g2m (r14-verified): bn1 -> conv2 -> bn2/relu -> max, grid-stride 768 ==========
__global__ __launch_bounds__(256) void k_g2m(
    const float* __restrict__ y1, const float* __restrict__ aff1,
    const float* __restrict__ Wt2, const float* __restrict__ b2,
    const float* __restrict__ aff2, float* __restrict__ out)
{
  __shared__ float XT[64*66];
  __shared__ float W2L[64*128];
  const int tid = threadIdx.x, lane = tid & 63;
  for (int i = tid; i < 64*128; i += 256) W2L[i] = Wt2[i];
  const float4* W2L4 = (const float4*)W2L;

  const int col0 = 2*(lane & 31);
  const int ob   = (tid >> 6)*32 + (lane >> 5)*16;

  for (int t = blockIdx.x; t < 8192; t += 768) {   // 8192 tiles of 64 cols
    int gcol = t*64;
    __syncthreads();
    stage_bn1(y1, aff1, XT, gcol, tid);
    __syncthreads();
    float acc0[16], acc1[16];
    #pragma unroll
    for (int i = 0; i < 16; ++i) { acc0[i] = b2[ob+i]; acc1[i] = acc0[i]; }
    for (int c = 0; c < 64; ++c) {
      float x0 = XT[c*66 + col0];
      float x1 = XT[c*66 + col0 + 1];
      #pragma unroll
      for (int i4 = 0; i4 < 4; ++i4) {
        float4 w = W2L4[c*32 + (ob>>2) + i4];
        acc0[i4*4+0] = fmaf(w.x, x0, acc0[i4*4+0]); acc1[i4*4+0] = fmaf(w.x, x1, acc1[i4*4+0]);
        acc0[i4*4+1] = fmaf(w.y, x0, acc0[i4*4+1]); acc1[i4*4+1] = fmaf(w.y, x1, acc1[i4*4+1]);
        acc0[i4*4+2] = fmaf(w.z, x0, acc0[i4*4+2]); acc1[i4*4+2] = fmaf(w.z, x1, acc1[i4*4+2]);
        acc0[i4*4+3] = fmaf(w.w, x0, acc0[i4*4+3]); acc1[i4*4+3] = fmaf(w.w, x1, acc1[i4*4+3]);
      }
    }
    // bn2 + relu + max over the 2 cols, then over 16-lane groups (one node each)
    float v[16];
    #pragma unroll
    for (int i = 0; i < 16; ++i) {
      int o = ob + i;
      float r0 = fmaxf(fmaf(acc0[i], aff2[o], aff2[128+o]), 0.f);
      float r1 = fmaxf(fmaf(acc1[i], aff2[o], aff2[128+o]), 0.f);
      v[i] = fmaxf(r0, r1);
      #pragma unroll
      for (int off = 1; off < 16; off <<= 1)
        v[i] = fmaxf(v[i], __shfl_xor(v[i], off, 64));
    }
    if ((lane & 15) == 0) {
      int node = (gcol >> 5) + ((lane >> 4) & 1);
      int b = node >> 11, m = node & 2047;
      float* op = out + ((size_t)b*128)*2048 + m;
      #pragma unroll
      for (int i = 0; i < 16; ++i)
        op[(size_t)(ob+i)*2048] = v[i];
    }
  }
}

extern "C" void kernel_launch(void* const* d_in, const int* in_sizes, int n_in,
                              void* d_out, int out_size, void* d_ws, size_t ws_size,
                              hipStream_t stream)
{
  const float* xyz   = (const float*)d_in[0];
  const float* feats = (const float*)d_in[1];
  const float* W0 = (const float*)d_in[2];
  const float* b0 = (const float*)d_in[3];
  const float* g0 = (const float*)d_in[4];
  const float* be0= (const float*)d_in[5];
  const float* W1 = (const float*)d_in[6];
  const float* b1 = (const float*)d_in[7];
  const float* g1 = (const float*)d_in[8];
  const float* be1= (const float*)d_in[9];
  const float* W2 = (const float*)d_in[10];
  const float* b2 = (const float*)d_in[11];
  const float* g2 = (const float*)d_in[12];
  const float* be2= (const float*)d_in[13];

  char* ws = (char*)d_ws;
  float* sx    = (float*)(ws + OFF_SX);
  int*   knn   = (int*  )(ws + OFF_KNN);
  float* ft    = (float*)(ws + OFF_FT);
  float* stats = (float*)(ws + OFF_ST);
  float* aff   = (float*)(ws + OFF_AF);
  float* Wt0   = (float*)(ws + OFF_W0);
  float* Wt1   = (float*)(ws + OFF_W1);
  float* Wt2   = (float*)(ws + OFF_W2);
  int*   mult  = (int*  )(ws + OFF_MULT);
  float* G0    = (float*)(ws + OFF_G0);
  float* G1    = (float*)(ws + OFF_G1);
  float* y1    = (float*)(ws + OFF_Y1);

  float* centers_out = (float*)d_out;              // 8*2048*3
  float* feat_out    = (float*)d_out + NNODE*3;    // 8*128*2048

  k_prep <<<256, 256, 0, stream>>>(xyz, W0, W1, W2, sx, Wt0, Wt1, Wt2, stats,
                                   centers_out, mult, G0, G1);
  k_ft   <<<1024, 256, 0, stream>>>(feats, ft);
  k_knn  <<<NNODE/4, 256, 0, stream>>>(xyz, sx, knn, mult);
  k_gram0<<<64, 256, 0, stream>>>(xyz, ft, mult, G0);
  k_fin0 <<<64, 64, 0, stream>>>(G0, W0, b0, g0, be0, aff + 0);
  k_g01  <<<768, 256, 0, stream>>>(xyz, ft, knn, Wt0, b0, aff + 0, Wt1, b1, y1, stats + 256);
  k_fin  <<<1, 128, 0, stream>>>(stats + 256, g1, be1, aff + 256, 64);
  k_gram1<<<512, 256, 0, stream>>>(y1, aff + 256, G1);
  k_fin2 <<<128, 64, 0, stream>>>(G1, W2, b2, g2, be2, aff + 512);
  k_g2m  <<<768, 256, 0, stream>>>(y1, aff + 256, Wt2, b2, aff + 512, feat_out);
}

// Round 20
// 985.009 us; speedup vs baseline: 1.4662x; 1.0029x over previous
//
#include <hip/hip_runtime.h>
#include <math.h>

#define B_    8
#define P_    8192
#define M_    2048
#define NNODE 16384      // B_*M_
#define NCOL  524288     // NNODE*32
#define EPS_  1e-5f

// ---- ws layout (bytes) ----
#define OFF_SX   0ull                        // 65536 f32
#define OFF_KNN  (OFF_SX + 262144ull)        // 524288 i32
#define OFF_FT   (OFF_KNN + 2097152ull)      // 8*8192*64 f32
#define OFF_ST   (OFF_FT + 16777216ull)      // 768 f32 (pad 4096)
#define OFF_AF   (OFF_ST + 4096ull)          // 768 f32 (pad 4096)
#define OFF_W0   (OFF_AF + 4096ull)          // 67*64 f32 = 17152
#define OFF_W1   (OFF_W0 + 17152ull)         // 64*64 f32 = 16384
#define OFF_W2   (OFF_W1 + 16384ull)         // 64*128 f32 = 32768
#define OFF_MULT (OFF_W2 + 32768ull)         // 65536 i32 = 262144
#define OFF_G0   (OFF_MULT + 262144ull)      // 68*68 f32 (pad 18560)
#define OFF_G1   (OFF_G0 + 18560ull)         // 68*68 f32 (pad 18560)
#define OFF_Y1   (OFF_G1 + 18560ull)         // 524288*64 f32 (16B-aligned)
// total ~154 MB

// ---------------- prep ----------------
__global__ __launch_bounds__(256) void k_prep(
    const float* __restrict__ xyz, const float* __restrict__ W0,
    const float* __restrict__ W1, const float* __restrict__ W2,
    float* __restrict__ sx, float* __restrict__ Wt0, float* __restrict__ Wt1,
    float* __restrict__ Wt2, float* __restrict__ stats, float* __restrict__ centers_out,
    int* __restrict__ mult, float* __restrict__ G0, float* __restrict__ G1)
{
  int idx = blockIdx.x*256 + threadIdx.x;
  if (idx < B_*P_) {
    const float* p3 = xyz + (size_t)idx*3;
    float x = p3[0], y = p3[1], z = p3[2];
    sx[idx] = __fadd_rn(__fadd_rn(__fmul_rn(x,x), __fmul_rn(y,y)), __fmul_rn(z,z));
    mult[idx] = 0;
  }
  if (idx < NNODE*3) {
    int m2 = idx/3, comp = idx - m2*3;
    int b = m2 >> 11, m = m2 & 2047;
    int cp = (m * 8191) / 2047;   // exact floor == int32(linspace), verified
    centers_out[idx] = xyz[((size_t)(b*P_ + cp))*3 + comp];
  }
  if (idx < 67*64) { int c = idx >> 6, o = idx & 63;  Wt0[idx] = W0[o*67 + c]; }
  if (idx < 64*64) { int c = idx >> 6, o = idx & 63;  Wt1[idx] = W1[o*64 + c]; }
  if (idx < 64*128){ int c = idx >> 7, o = idx & 127; Wt2[idx] = W2[o*64 + c]; }
  if (idx < 768)   stats[idx] = 0.f;
  if (idx < 4624)  { G0[idx] = 0.f; G1[idx] = 0.f; }
}

// ---------------- feats (b,c,p) -> ft (b,p,c) ----------------
__global__ __launch_bounds__(256) void k_ft(const float* __restrict__ feats, float* __restrict__ ft)
{
  int blk = blockIdx.x;            // 8*128
  int b = blk >> 7; int pt = (blk & 127) * 64;
  __shared__ float tile[64][65];
  const float* fb = feats + (size_t)b*64*P_;
  int tid = threadIdx.x;
  #pragma unroll
  for (int i = 0; i < 16; ++i) {
    int idx = i*256 + tid; int c = idx >> 6, p = idx & 63;
    tile[c][p] = fb[(size_t)c*P_ + pt + p];
  }
  __syncthreads();
  float* fo = ft + ((size_t)b*P_ + pt)*64;
  #pragma unroll
  for (int i = 0; i < 16; ++i) {
    int idx = i*256 + tid; int p = idx >> 6, c = idx & 63;
    fo[(size_t)p*64 + c] = tile[c][p];
  }
}

// ---------------- KNN v3 + fused mult histogram (VERIFIED r17) ----------------
__global__ __launch_bounds__(256) void k_knn(const float* __restrict__ xyz,
                                             const float* __restrict__ sx,
                                             int* __restrict__ knn,
                                             int* __restrict__ mult)
{
  const int tid = threadIdx.x;
  const int lane = tid & 63, w = tid >> 6;
  const int cid = blockIdx.x*4 + w;
  const int b = cid >> 11, m = cid & 2047;
  const int cp = (m * 8191) / 2047;
  const float* xb  = xyz + (size_t)b * P_ * 3;
  const float* sxb = sx + b * P_;
  const float cx = xb[cp*3+0], cy = xb[cp*3+1], cz = xb[cp*3+2];
  const float sc = sxb[cp];
  const unsigned long long EMPTY = ~0ull;

  unsigned long long l0 = EMPTY, l1 = EMPTY, l2 = EMPTY, l3 = EMPTY;

  #pragma unroll 4
  for (int i = 0; i < 128; ++i) {
    int p = i*64 + lane;
    float px = xb[p*3+0], py = xb[p*3+1], pz = xb[p*3+2];
    float dot = fmaf(cz, pz, fmaf(cy, py, __fmul_rn(cx, px)));
    float fk  = __fsub_rn(__fadd_rn(sc, sxb[p]), __fmul_rn(2.0f, dot));
    unsigned ub = __float_as_uint(fk);
    unsigned su = ub ^ (0x80000000u | (unsigned)((int)ub >> 31));  // sortable f32
    unsigned long long k = ((unsigned long long)su << 13) | (unsigned)p;
    unsigned long long m3 = k < l3 ? k : l3;
    bool c2 = m3 < l2;
    unsigned long long n2 = c2 ? m3 : l2, n3 = c2 ? l2 : m3;
    bool c1 = n2 < l1;
    unsigned long long n1 = c1 ? n2 : l1; n2 = c1 ? l1 : n2;
    bool c0 = n1 < l0;
    unsigned long long nl0 = c0 ? n1 : l0; n1 = c0 ? l0 : n1;
    l0 = nl0; l1 = n1; l2 = n2; l3 = n3;
  }

  int* kout = knn + cid*32;
  for (int r = 0; r < 32; ++r) {
    unsigned long long mn = l0;
    #pragma unroll
    for (int off = 1; off < 64; off <<= 1) {
      unsigned long long o = __shfl_xor(mn, off, 64);
      if (o < mn) mn = o;
    }
    if (lane == 0) kout[r] = (int)(mn & 8191u);
    bool mine = ((int)(mn & 63u) == lane);
    if (mine) {
      atomicAdd(&mult[b*P_ + (int)(mn & 8191u)], 1);   // fused histogram
      l0 = l1; l1 = l2; l2 = l3; l3 = EMPTY;
    }
    if (mine && l0 == EMPTY) {
      #pragma unroll 1
      for (int i = 0; i < 128; ++i) {
        int p = i*64 + lane;
        float px = xb[p*3+0], py = xb[p*3+1], pz = xb[p*3+2];
        float dot = fmaf(cz, pz, fmaf(cy, py, __fmul_rn(cx, px)));
        float fk  = __fsub_rn(__fadd_rn(sc, sxb[p]), __fmul_rn(2.0f, dot));
        unsigned ub = __float_as_uint(fk);
        unsigned su = ub ^ (0x80000000u | (unsigned)((int)ub >> 31));
        unsigned long long k = ((unsigned long long)su << 13) | (unsigned)p;
        k = (k > mn) ? k : EMPTY;
        unsigned long long m3 = k < l3 ? k : l3;
        bool c2 = m3 < l2;
        unsigned long long n2 = c2 ? m3 : l2, n3 = c2 ? l2 : m3;
        bool c1 = n2 < l1;
        unsigned long long n1 = c1 ? n2 : l1; n2 = c1 ? l1 : n2;
        bool c0 = n1 < l0;
        unsigned long long nl0 = c0 ? n1 : l0; n1 = c0 ? l0 : n1;
        l0 = nl0; l1 = n1; l2 = n2; l3 = n3;
      }
    }
  }
}

// ---------------- k_gram0: weighted Gram of X0 (r17-verified full tiles) ----------------
__global__ __launch_bounds__(256) void k_gram0(
    const float* __restrict__ xyz, const float* __restrict__ ft,
    const int* __restrict__ mult, float* __restrict__ G0)
{
  __shared__ float X[64*68];
  __shared__ float ML[64];
  const int tid = threadIdx.x;
  const int t0 = tid;                 // tile ids in [0,289): 17x17 of 4x4
  const int t1 = 256 + tid;           // valid for tid < 33
  const int ta0 = t0/17, tb0 = t0%17;
  const int ta1 = t1/17, tb1 = t1%17;
  float acc0[16], acc1[16];
  #pragma unroll
  for (int i = 0; i < 16; ++i) { acc0[i] = 0.f; acc1[i] = 0.f; }
  const float4* X4 = (const float4*)X;

  for (int ch = 0; ch < 16; ++ch) {
    int q0 = blockIdx.x*1024 + ch*64;
    __syncthreads();
    {
      int lp = tid >> 2, part = tid & 3;
      int q = q0 + lp; int b = q >> 13, p = q & 8191;
      const float4* fp4 = (const float4*)(ft + ((size_t)(b*P_ + p))*64 + part*16);
      #pragma unroll
      for (int j4 = 0; j4 < 4; ++j4) {
        float4 v = fp4[j4];
        int c = 3 + part*16 + j4*4;
        X[lp*68 + c+0] = v.x; X[lp*68 + c+1] = v.y;
        X[lp*68 + c+2] = v.z; X[lp*68 + c+3] = v.w;
      }
      if (part == 0) {
        const float* xp = xyz + ((size_t)(b*P_ + p))*3;
        X[lp*68 + 0] = xp[0]; X[lp*68 + 1] = xp[1]; X[lp*68 + 2] = xp[2];
      }
      if (part == 1) X[lp*68 + 67] = 1.f;
      if (part == 2) ML[lp] = (float)mult[b*P_ + p];
    }
    __syncthreads();
    for (int lp = 0; lp < 64; ++lp) {
      float mw = ML[lp];
      {
        float4 xa = X4[lp*17 + ta0];
        float4 xb = X4[lp*17 + tb0];
        float wa0 = xa.x*mw, wa1 = xa.y*mw, wa2 = xa.z*mw, wa3 = xa.w*mw;
        acc0[0]  = fmaf(wa0, xb.x, acc0[0]);  acc0[1]  = fmaf(wa0, xb.y, acc0[1]);
        acc0[2]  = fmaf(wa0, xb.z, acc0[2]);  acc0[3]  = fmaf(wa0, xb.w, acc0[3]);
        acc0[4]  = fmaf(wa1, xb.x, acc0[4]);  acc0[5]  = fmaf(wa1, xb.y, acc0[5]);
        acc0[6]  = fmaf(wa1, xb.z, acc0[6]);  acc0[7]  = fmaf(wa1, xb.w, acc0[7]);
        acc0[8]  = fmaf(wa2, xb.x, acc0[8]);  acc0[9]  = fmaf(wa2, xb.y, acc0[9]);
        acc0[10] = fmaf(wa2, xb.z, acc0[10]); acc0[11] = fmaf(wa2, xb.w, acc0[11]);
        acc0[12] = fmaf(wa3, xb.x, acc0[12]); acc0[13] = fmaf(wa3, xb.y, acc0[13]);
        acc0[14] = fmaf(wa3, xb.z, acc0[14]); acc0[15] = fmaf(wa3, xb.w, acc0[15]);
      }
      if (tid < 33) {
        float4 xa = X4[lp*17 + ta1];
        float4 xb = X4[lp*17 + tb1];
        float wa0 = xa.x*mw, wa1 = xa.y*mw, wa2 = xa.z*mw, wa3 = xa.w*mw;
        acc1[0]  = fmaf(wa0, xb.x, acc1[0]);  acc1[1]  = fmaf(wa0, xb.y, acc1[1]);
        acc1[2]  = fmaf(wa0, xb.z, acc1[2]);  acc1[3]  = fmaf(wa0, xb.w, acc1[3]);
        acc1[4]  = fmaf(wa1, xb.x, acc1[4]);  acc1[5]  = fmaf(wa1, xb.y, acc1[5]);
        acc1[6]  = fmaf(wa1, xb.z, acc1[6]);  acc1[7]  = fmaf(wa1, xb.w, acc1[7]);
        acc1[8]  = fmaf(wa2, xb.x, acc1[8]);  acc1[9]  = fmaf(wa2, xb.y, acc1[9]);
        acc1[10] = fmaf(wa2, xb.z, acc1[10]); acc1[11] = fmaf(wa2, xb.w, acc1[11]);
        acc1[12] = fmaf(wa3, xb.x, acc1[12]); acc1[13] = fmaf(wa3, xb.y, acc1[13]);
        acc1[14] = fmaf(wa3, xb.z, acc1[14]); acc1[15] = fmaf(wa3, xb.w, acc1[15]);
      }
    }
  }
  #pragma unroll
  for (int i = 0; i < 4; ++i)
    #pragma unroll
    for (int j = 0; j < 4; ++j)
      atomicAdd(&G0[(ta0*4+i)*68 + tb0*4+j], acc0[i*4+j]);
  if (tid < 33) {
    #pragma unroll
    for (int i = 0; i < 4; ++i)
      #pragma unroll
      for (int j = 0; j < 4; ++j)
        atomicAdd(&G0[(ta1*4+i)*68 + tb1*4+j], acc1[i*4+j]);
  }
}

// ---------------- k_fin0 v2: PARALLEL quadform (64 blocks x 64 thr) ----------------
__global__ void k_fin0(const float* __restrict__ G, const float* __restrict__ W0,
                       const float* __restrict__ b0, const float* __restrict__ g,
                       const float* __restrict__ be, float* __restrict__ aff)
{
  const int o = blockIdx.x;          // 64 outputs
  const int c = threadIdx.x;         // 64 threads
  const float* w = W0 + o*67;
  double part = 0.0, wsp = 0.0;
  for (int cc = c; cc < 67; cc += 64) {
    double row = 0.0;
    for (int d = 0; d < 67; ++d) row += (double)w[d] * (double)G[cc*68 + d];
    part += (double)w[cc] * row;
    wsp  += (double)w[cc] * (double)G[cc*68 + 67];
  }
  #pragma unroll
  for (int off = 1; off < 64; off <<= 1) {
    part += __shfl_xor(part, off, 64);
    wsp  += __shfl_xor(wsp,  off, 64);
  }
  if (c == 0) {
    double N = (double)NCOL, bb = (double)b0[o];
    double sum = wsp + N*bb;
    double sq  = part + 2.0*bb*wsp + N*bb*bb;
    double mu = sum/N, var = sq/N - mu*mu;
    float r = 1.0f / sqrtf((float)var + EPS_);
    float s = g[o]*r;
    aff[o] = s;
    aff[128+o] = fmaf(-(float)mu, s, be[o]);
  }
}

// ========== k_g01 (r14-verified): conv0 -> bn0/relu -> conv1, grid-stride 768 ==========
__global__ __launch_bounds__(256) void k_g01(
    const float* __restrict__ xyz, const float* __restrict__ ft,
    const int* __restrict__ knn, const float* __restrict__ Wt0,
    const float* __restrict__ b0, const float* __restrict__ aff0,
    const float* __restrict__ Wt1, const float* __restrict__ b1,
    float* __restrict__ y1, float* __restrict__ stats1)
{
  __shared__ float S[67*66];             // X0T [67][66] then A0T [64][66]
  __shared__ float W0L[67*64];
  __shared__ float W1L[64*64];
  const int tid = threadIdx.x, lane = tid & 63;
  for (int i = tid; i < 67*64; i += 256) W0L[i] = Wt0[i];
  for (int i = tid; i < 64*64; i += 256) W1L[i] = Wt1[i];
  const float4* W0L4 = (const float4*)W0L;
  const float4* W1L4 = (const float4*)W1L;

  const int col0 = 2*(lane & 31);        // 64 cols
  const int og   = tid >> 5;             // 8 out-groups x 8
  const int ob   = og * 8;
  float ts[8], tq[8];
  #pragma unroll
  for (int i = 0; i < 8; ++i) { ts[i] = 0.f; tq[i] = 0.f; }

  for (int t = blockIdx.x; t < 8192; t += 768) {   // 8192 tiles of 64 cols
    int gcol = t*64;
    int b = gcol >> 16;
    __syncthreads();
    {   // stage gather: col = tid&63, q = tid>>6
      int scol = tid & 63, q = tid >> 6;
      int p = knn[gcol + scol];
      if (q == 0) {
        const float* xp = xyz + ((size_t)(b*P_ + p))*3;
        S[0*66 + scol] = xp[0];
        S[1*66 + scol] = xp[1];
        S[2*66 + scol] = xp[2];
      }
      const float4* fp4 = (const float4*)(ft + ((size_t)(b*P_ + p))*64 + q*16);
      #pragma unroll
      for (int j4 = 0; j4 < 4; ++j4) {
        float4 v = fp4[j4];
        int r = 3 + q*16 + j4*4;
        S[(r+0)*66 + scol] = v.x;
        S[(r+1)*66 + scol] = v.y;
        S[(r+2)*66 + scol] = v.z;
        S[(r+3)*66 + scol] = v.w;
      }
    }
    __syncthreads();
    // conv0 GEMM
    float acc0[8], acc1[8];
    #pragma unroll
    for (int i = 0; i < 8; ++i) { acc0[i] = b0[ob+i]; acc1[i] = acc0[i]; }
    for (int c = 0; c < 67; ++c) {
      float2 xp = *(const float2*)(S + c*66 + col0);
      float x0 = xp.x, x1 = xp.y;
      #pragma unroll
      for (int i4 = 0; i4 < 2; ++i4) {
        float4 w = W0L4[c*16 + og*2 + i4];
        acc0[i4*4+0] = fmaf(w.x, x0, acc0[i4*4+0]); acc1[i4*4+0] = fmaf(w.x, x1, acc1[i4*4+0]);
        acc0[i4*4+1] = fmaf(w.y, x0, acc0[i4*4+1]); acc1[i4*4+1] = fmaf(w.y, x1, acc1[i4*4+1]);
        acc0[i4*4+2] = fmaf(w.z, x0, acc0[i4*4+2]); acc1[i4*4+2] = fmaf(w.z, x1, acc1[i4*4+2]);
        acc0[i4*4+3] = fmaf(w.w, x0, acc0[i4*4+3]); acc1[i4*4+3] = fmaf(w.w, x1, acc1[i4*4+3]);
      }
    }
    // bn0 + relu
    #pragma unroll
    for (int i = 0; i < 8; ++i) {
      int o = ob + i;
      acc0[i] = fmaxf(fmaf(acc0[i], aff0[o], aff0[128+o]), 0.f);
      acc1[i] = fmaxf(fmaf(acc1[i], aff0[o], aff0[128+o]), 0.f);
    }
    __syncthreads();                     // all X0T reads done before overwrite
    #pragma unroll
    for (int i = 0; i < 8; ++i)
      *(float2*)(S + (ob+i)*66 + col0) = make_float2(acc0[i], acc1[i]);
    __syncthreads();
    // conv1 GEMM
    float d0[8], d1[8];
    #pragma unroll
    for (int i = 0; i < 8; ++i) { d0[i] = b1[ob+i]; d1[i] = d0[i]; }
    for (int c = 0; c < 64; ++c) {
      float2 xp = *(const float2*)(S + c*66 + col0);
      float x0 = xp.x, x1 = xp.y;
      #pragma unroll
      for (int i4 = 0; i4 < 2; ++i4) {
        float4 w = W1L4[c*16 + og*2 + i4];
        d0[i4*4+0] = fmaf(w.x, x0, d0[i4*4+0]); d1[i4*4+0] = fmaf(w.x, x1, d1[i4*4+0]);
        d0[i4*4+1] = fmaf(w.y, x0, d0[i4*4+1]); d1[i4*4+1] = fmaf(w.y, x1, d1[i4*4+1]);
        d0[i4*4+2] = fmaf(w.z, x0, d0[i4*4+2]); d1[i4*4+2] = fmaf(w.z, x1, d1[i4*4+2]);
        d0[i4*4+3] = fmaf(w.w, x0, d0[i4*4+3]); d1[i4*4+3] = fmaf(w.w, x1, d1[i4*4+3]);
      }
    }
    // store y1 + accumulate stats1
    float* yr0 = y1 + (size_t)(gcol + col0)*64 + ob;
    *(float4*)(yr0)     = make_float4(d0[0], d0[1], d0[2], d0[3]);
    *(float4*)(yr0 + 4) = make_float4(d0[4], d0[5], d0[6], d0[7]);
    float* yr1 = y1 + (size_t)(gcol + col0 + 1)*64 + ob;
    *(float4*)(yr1)     = make_float4(d1[0], d1[1], d1[2], d1[3]);
    *(float4*)(yr1 + 4) = make_float4(d1[4], d1[5], d1[6], d1[7]);
    #pragma unroll
    for (int i = 0; i < 8; ++i) {
      ts[i] += d0[i] + d1[i];
      tq[i] += d0[i]*d0[i] + d1[i]*d1[i];
    }
  }
  #pragma unroll
  for (int i = 0; i < 8; ++i) {
    float s = ts[i], q = tq[i];
    #pragma unroll
    for (int off = 1; off < 32; off <<= 1) {
      s += __shfl_xor(s, off, 64);
      q += __shfl_xor(q, off, 64);
    }
    if ((lane & 31) == 0) { atomicAdd(&stats1[ob+i], s); atomicAdd(&stats1[128+ob+i], q); }
  }
}

// ---------------- BN finalize (layer 1, from direct stats) ----------------
__global__ void k_fin(const float* __restrict__ stats, const float* __restrict__ g,
                      const float* __restrict__ be, float* __restrict__ aff, int C)
{
  int o = threadIdx.x;
  if (o < C) {
    float N = (float)NCOL;
    float mu = stats[o] / N;
    float var = stats[128+o]/N - mu*mu;
    float r = 1.0f / sqrtf(var + EPS_);
    float s = g[o]*r;
    aff[o] = s;
    aff[128+o] = fmaf(-mu, s, be[o]);
  }
}

// ---------------- k_gram1: Gram of a1 (r17-verified full tiles) ----------------
__global__ __launch_bounds__(256) void k_gram1(
    const float* __restrict__ y1, const float* __restrict__ aff1,
    float* __restrict__ G1)
{
  __shared__ float A[64*68];
  const int tid = threadIdx.x;
  const int t0 = tid, t1 = 256 + tid;
  const int ta0 = t0/17, tb0 = t0%17;
  const int ta1 = t1/17, tb1 = t1%17;
  float acc0[16], acc1[16];
  #pragma unroll
  for (int i = 0; i < 16; ++i) { acc0[i] = 0.f; acc1[i] = 0.f; }
  const float4* A4 = (const float4*)A;

  for (int ch = 0; ch < 16; ++ch) {
    int gcol = blockIdx.x*1024 + ch*64;
    __syncthreads();
    {
      int lc = tid >> 2, part = tid & 3;
      const float4* yp = (const float4*)(y1 + (size_t)(gcol + lc)*64 + part*16);
      #pragma unroll
      for (int j4 = 0; j4 < 4; ++j4) {
        float4 v = yp[j4];
        int c = part*16 + j4*4;
        A[lc*68 + c+0] = fmaxf(fmaf(v.x, aff1[c+0], aff1[128+c+0]), 0.f);
        A[lc*68 + c+1] = fmaxf(fmaf(v.y, aff1[c+1], aff1[128+c+1]), 0.f);
        A[lc*68 + c+2] = fmaxf(fmaf(v.z, aff1[c+2], aff1[128+c+2]), 0.f);
        A[lc*68 + c+3] = fmaxf(fmaf(v.w, aff1[c+3], aff1[128+c+3]), 0.f);
      }
      if (part == 1) A[lc*68 + 64] = 1.f;
      if (part == 2) { A[lc*68 + 65] = 0.f; A[lc*68 + 66] = 0.f; A[lc*68 + 67] = 0.f; }
    }
    __syncthreads();
    for (int lc = 0; lc < 64; ++lc) {
      {
        float4 xa = A4[lc*17 + ta0];
        float4 xb = A4[lc*17 + tb0];
        acc0[0]  = fmaf(xa.x, xb.x, acc0[0]);  acc0[1]  = fmaf(xa.x, xb.y, acc0[1]);
        acc0[2]  = fmaf(xa.x, xb.z, acc0[2]);  acc0[3]  = fmaf(xa.x, xb.w, acc0[3]);
        acc0[4]  = fmaf(xa.y, xb.x, acc0[4]);  acc0[5]  = fmaf(xa.y, xb.y, acc0[5]);
        acc0[6]  = fmaf(xa.y, xb.z, acc0[6]);  acc0[7]  = fmaf(xa.y, xb.w, acc0[7]);
        acc0[8]  = fmaf(xa.z, xb.x, acc0[8]);  acc0[9]  = fmaf(xa.z, xb.y, acc0[9]);
        acc0[10] = fmaf(xa.z, xb.z, acc0[10]); acc0[11] = fmaf(xa.z, xb.w, acc0[11]);
        acc0[12] = fmaf(xa.w, xb.x, acc0[12]); acc0[13] = fmaf(xa.w, xb.y, acc0[13]);
        acc0[14] = fmaf(xa.w, xb.z, acc0[14]); acc0[15] = fmaf(xa.w, xb.w, acc0[15]);
      }
      if (tid < 33) {
        float4 xa = A4[lc*17 + ta1];
        float4 xb = A4[lc*17 + tb1];
        acc1[0]  = fmaf(xa.x, xb.x, acc1[0]);  acc1[1]  = fmaf(xa.x, xb.y, acc1[1]);
        acc1[2]  = fmaf(xa.x, xb.z, acc1[2]);  acc1[3]  = fmaf(xa.x, xb.w, acc1[3]);
        acc1[4]  = fmaf(xa.y, xb.x, acc1[4]);  acc1[5]  = fmaf(xa.y, xb.y, acc1[5]);
        acc1[6]  = fmaf(xa.y, xb.z, acc1[6]);  acc1[7]  = fmaf(xa.y, xb.w, acc1[7]);
        acc1[8]  = fmaf(xa.z, xb.x, acc1[8]);  acc1[9]  = fmaf(xa.z, xb.y, acc1[9]);
        acc1[10] = fmaf(xa.z, xb.z, acc1[10]); acc1[11] = fmaf(xa.z, xb.w, acc1[11]);
        acc1[12] = fmaf(xa.w, xb.x, acc1[12]); acc1[13] = fmaf(xa.w, xb.y, acc1[13]);
        acc1[14] = fmaf(xa.w, xb.z, acc1[14]); acc1[15] = fmaf(xa.w, xb.w, acc1[15]);
      }
    }
  }
  #pragma unroll
  for (int i = 0; i < 4; ++i)
    #pragma unroll
    for (int j = 0; j < 4; ++j)
      atomicAdd(&G1[(ta0*4+i)*68 + tb0*4+j], acc0[i*4+j]);
  if (tid < 33) {
    #pragma unroll
    for (int i = 0; i < 4; ++i)
      #pragma unroll
      for (int j = 0; j < 4; ++j)
        atomicAdd(&G1[(ta1*4+i)*68 + tb1*4+j], acc1[i*4+j]);
  }
}

// ---------------- k_fin2 v2: PARALLEL quadform (128 blocks x 64 thr) ----------------
__global__ void k_fin2(const float* __restrict__ G, const float* __restrict__ W2,
                       const float* __restrict__ b2, const float* __restrict__ g,
                       const float* __restrict__ be, float* __restrict__ aff)
{
  const int o = blockIdx.x;          // 128 outputs
  const int c = threadIdx.x;         // 64 threads
  const float* w = W2 + o*64;
  double row = 0.0;
  for (int d = 0; d < 64; ++d) row += (double)w[d] * (double)G[c*68 + d];
  double part = (double)w[c] * row;
  double wsp  = (double)w[c] * (double)G[c*68 + 64];
  #pragma unroll
  for (int off = 1; off < 64; off <<= 1) {
    part += __shfl_xor(part, off, 64);
    wsp  += __shfl_xor(wsp,  off, 64);
  }
  if (c == 0) {
    double N = (double)NCOL, bb = (double)b2[o];
    double sum = wsp + N*bb;
    double sq  = part + 2.0*bb*wsp + N*bb*bb;
    double mu = sum/N, var = sq/N - mu*mu;
    float r = 1.0f / sqrtf((float)var + EPS_);
    float s = g[o]*r;
    aff[o] = s;
    aff[128+o] = fmaf(-(float)mu, s, be[o]);
  }
}

// ========== shared stage for conv2: bn1(y1) -> XT[64][66] (r10-verified) ==========
__device__ __forceinline__ void stage_bn1(const float* __restrict__ y1,
                                          const float* __restrict__ aff1,
                                          float* __restrict__ XT, int gcol, int tid)
{
  int scol = tid & 63, q = tid >> 6;
  const float4* yp = (const float4*)(y1 + (size_t)(gcol + scol)*64 + q*16);
  #pragma unroll
  for (int j4 = 0; j4 < 4; ++j4) {
    float4 v = yp[j4];
    int c = q*16 + j4*4;
    XT[(c+0)*66 + scol] = fmaxf(fmaf(v.x, aff1[c+0], aff1[128+c+0]), 0.f);
    XT[(c+1)*66 + scol] = fmaxf(fmaf(v.y, aff1[c+1], aff1[128+c+1]), 0.f);
    XT[(c+2)*66 + scol] = fmaxf(fmaf(v.z, aff1[c+2], aff1[128+c+2]), 0.f);
    XT[(c+3)*66 + scol] = fmaxf(fmaf(v.w, aff1[c+3], aff1[128+c+3]), 0.f);
  }
}

// ========== k_g2m (r14-verified): bn1 -> conv2 -> bn2/relu -> max, grid-stride 768 ==========
__global__ __launch_bounds__(256) void k_g2m(
    const float* __restrict__ y1, const float* __restrict__ aff1,
    const float* __restrict__ Wt2, const float* __restrict__ b2,
    const float* __restrict__ aff2, float* __restrict__ out)
{
  __shared__ float XT[64*66];
  __shared__ float W2L[64*128];
  const int tid = threadIdx.x, lane = tid & 63;
  for (int i = tid; i < 64*128; i += 256) W2L[i] = Wt2[i];
  const float4* W2L4 = (const float4*)W2L;

  const int col0 = 2*(lane & 31);
  const int ob   = (tid >> 6)*32 + (lane >> 5)*16;

  for (int t = blockIdx.x; t < 8192; t += 768) {   // 8192 tiles of 64 cols
    int gcol = t*64;
    __syncthreads();
    stage_bn1(y1, aff1, XT, gcol, tid);
    __syncthreads();
    float acc0[16], acc1[16];
    #pragma unroll
    for (int i = 0; i < 16; ++i) { acc0[i] = b2[ob+i]; acc1[i] = acc0[i]; }
    for (int c = 0; c < 64; ++c) {
      float x0 = XT[c*66 + col0];
      float x1 = XT[c*66 + col0 + 1];
      #pragma unroll
      for (int i4 = 0; i4 < 4; ++i4) {
        float4 w = W2L4[c*32 + (ob>>2) + i4];
        acc0[i4*4+0] = fmaf(w.x, x0, acc0[i4*4+0]); acc1[i4*4+0] = fmaf(w.x, x1, acc1[i4*4+0]);
        acc0[i4*4+1] = fmaf(w.y, x0, acc0[i4*4+1]); acc1[i4*4+1] = fmaf(w.y, x1, acc1[i4*4+1]);
        acc0[i4*4+2] = fmaf(w.z, x0, acc0[i4*4+2]); acc1[i4*4+2] = fmaf(w.z, x1, acc1[i4*4+2]);
        acc0[i4*4+3] = fmaf(w.w, x0, acc0[i4*4+3]); acc1[i4*4+3] = fmaf(w.w, x1, acc1[i4*4+3]);
      }
    }
    // bn2 + relu + max over the 2 cols, then over 16-lane groups (one node each)
    float v[16];
    #pragma unroll
    for (int i = 0; i < 16; ++i) {
      int o = ob + i;
      float r0 = fmaxf(fmaf(acc0[i], aff2[o], aff2[128+o]), 0.f);
      float r1 = fmaxf(fmaf(acc1[i], aff2[o], aff2[128+o]), 0.f);
      v[i] = fmaxf(r0, r1);
      #pragma unroll
      for (int off = 1; off < 16; off <<= 1)
        v[i] = fmaxf(v[i], __shfl_xor(v[i], off, 64));
    }
    if ((lane & 15) == 0) {
      int node = (gcol >> 5) + ((lane >> 4) & 1);
      int b = node >> 11, m = node & 2047;
      float* op = out + ((size_t)b*128)*2048 + m;
      #pragma unroll
      for (int i = 0; i < 16; ++i)
        op[(size_t)(ob+i)*2048] = v[i];
    }
  }
}

extern "C" void kernel_launch(void* const* d_in, const int* in_sizes, int n_in,
                              void* d_out, int out_size, void* d_ws, size_t ws_size,
                              hipStream_t stream)
{
  const float* xyz   = (const float*)d_in[0];
  const float* feats = (const float*)d_in[1];
  const float* W0 = (const float*)d_in[2];
  const float* b0 = (const float*)d_in[3];
  const float* g0 = (const float*)d_in[4];
  const float* be0= (const float*)d_in[5];
  const float* W1 = (const float*)d_in[6];
  const float* b1 = (const float*)d_in[7];
  const float* g1 = (const float*)d_in[8];
  const float* be1= (const float*)d_in[9];
  const float* W2 = (const float*)d_in[10];
  const float* b2 = (const float*)d_in[11];
  const float* g2 = (const float*)d_in[12];
  const float* be2= (const float*)d_in[13];

  char* ws = (char*)d_ws;
  float* sx    = (float*)(ws + OFF_SX);
  int*   knn   = (int*  )(ws + OFF_KNN);
  float* ft    = (float*)(ws + OFF_FT);
  float* stats = (float*)(ws + OFF_ST);
  float* aff   = (float*)(ws + OFF_AF);
  float* Wt0   = (float*)(ws + OFF_W0);
  float* Wt1   = (float*)(ws + OFF_W1);
  float* Wt2   = (float*)(ws + OFF_W2);
  int*   mult  = (int*  )(ws + OFF_MULT);
  float* G0    = (float*)(ws + OFF_G0);
  float* G1    = (float*)(ws + OFF_G1);
  float* y1    = (float*)(ws + OFF_Y1);

  float* centers_out = (float*)d_out;              // 8*2048*3
  float* feat_out    = (float*)d_out + NNODE*3;    // 8*128*2048

  k_prep <<<256, 256, 0, stream>>>(xyz, W0, W1, W2, sx, Wt0, Wt1, Wt2, stats,
                                   centers_out, mult, G0, G1);
  k_ft   <<<1024, 256, 0, stream>>>(feats, ft);
  k_knn  <<<NNODE/4, 256, 0, stream>>>(xyz, sx, knn, mult);
  k_gram0<<<64, 256, 0, stream>>>(xyz, ft, mult, G0);
  k_fin0 <<<64, 64, 0, stream>>>(G0, W0, b0, g0, be0, aff + 0);
  k_g01  <<<768, 256, 0, stream>>>(xyz, ft, knn, Wt0, b0, aff + 0, Wt1, b1, y1, stats + 256);
  k_fin  <<<1, 128, 0, stream>>>(stats + 256, g1, be1, aff + 256, 64);
  k_gram1<<<512, 256, 0, stream>>>(y1, aff + 256, G1);
  k_fin2 <<<128, 64, 0, stream>>>(G1, W2, b2, g2, be2, aff + 512);
  k_g2m  <<<768, 256, 0, stream>>>(y1, aff + 256, Wt2, b2, aff + 512, feat_out);
}